// Round 1
// baseline (672.340 us; speedup 1.0000x reference)
//
#include <hip/hip_runtime.h>
#include <math.h>

// ---------------- problem constants ----------------
#define GAMMA_ 0.01f
#define WARP_  134.4f
#define INFV   100000.0f
#define BIGV   1000000000.0f

#define B_  4
#define H_  192
#define TP_ 350
#define TQ_ 400

// ---------------- workspace layout (float offsets) ----------------
// acc[0]=gen acc[1]=e2e acc[2]=fm acc[3]=mel acc[4]=dur acc[5]=sum_pm acc[6]=sum_qm
#define ACC_OFF 0
#define DTW_OFF 16                         // 8 results: [which*4 + b]
#define SLP_OFF 32                         // sum_h logs_p  [B][350]
#define SLQ_OFF (SLP_OFF + B_*TP_)         // sum_h logs_q  [B][400]
#define KL1_OFF 3072                       // kl1 [B][350][400], pitch 400
#define KL1_PITCH 400
#define KL2_OFF (KL1_OFF + B_*TP_*KL1_PITCH)   // kl2 [B][400][352], pitch 352
#define KL2_PITCH 352
// total = 563072 + 4*400*352 = 1126272 floats = 4,505,088 bytes (needs ws_size >= ~4.5MB)

__global__ void zero_kernel(float* ws) {
    int t = threadIdx.x;
    if (t < 32) ws[t] = 0.f;
}

// per-position sums over h of logs_p / logs_q
__global__ void sl_kernel(const float* __restrict__ logs_p,
                          const float* __restrict__ logs_q,
                          float* __restrict__ ws) {
    int t = blockIdx.x * 256 + threadIdx.x;
    if (t < B_ * TP_) {
        int b = t / TP_, i = t % TP_;
        const float* p = logs_p + (size_t)b * H_ * TP_ + i;
        float s = 0.f;
        for (int h = 0; h < H_; ++h) s += p[(size_t)h * TP_];
        ws[SLP_OFF + t] = s;
    } else if (t < B_ * TP_ + B_ * TQ_) {
        int t2 = t - B_ * TP_;
        int b = t2 / TQ_, j = t2 % TQ_;
        const float* p = logs_q + (size_t)b * H_ * TQ_ + j;
        float s = 0.f;
        for (int h = 0; h < H_; ++h) s += p[(size_t)h * TQ_];
        ws[SLQ_OFF + t2] = s;
    }
}

// kl[b,i,j] = SLrow[b,i] - SLcol[b,j] - 0.5*H + 0.5 * sum_h w[h,i]*(z[h,j]-m[h,i])^2
// w = exp(-2*ls[h,i]).  32x32 output tile per block, 2x2 per thread, K staged in LDS.
__global__ void kl_kernel(const float* __restrict__ mS, const float* __restrict__ lsS,
                          const float* __restrict__ zT,
                          const float* __restrict__ SLrow, const float* __restrict__ SLcol,
                          float* __restrict__ out, int R, int C, int pitch) {
    int b  = blockIdx.z;
    int i0 = blockIdx.y * 32, j0 = blockIdx.x * 32;
    __shared__ __align__(16) float wS [16][32];
    __shared__ __align__(16) float mSh[16][32];
    __shared__ __align__(16) float zSh[16][32];
    const float* mB = mS  + (size_t)b * H_ * R;
    const float* lB = lsS + (size_t)b * H_ * R;
    const float* zB = zT  + (size_t)b * H_ * C;
    int tx = threadIdx.x, ty = threadIdx.y;
    int t  = ty * 16 + tx;
    float a00 = 0.f, a01 = 0.f, a10 = 0.f, a11 = 0.f;
    for (int h0 = 0; h0 < H_; h0 += 16) {
        for (int e = t; e < 512; e += 256) {
            int hh = e >> 5, cc = e & 31;
            int h = h0 + hh;
            int gi = i0 + cc;
            float wv = 0.f, mv = 0.f;
            if (gi < R) {
                wv = __expf(-2.f * lB[(size_t)h * R + gi]);
                mv = mB[(size_t)h * R + gi];
            }
            wS[hh][cc] = wv; mSh[hh][cc] = mv;
            int gj = j0 + cc;
            zSh[hh][cc] = (gj < C) ? zB[(size_t)h * C + gj] : 0.f;
        }
        __syncthreads();
#pragma unroll
        for (int kk = 0; kk < 16; ++kk) {
            float2 wv = *(const float2*)&wS [kk][ty * 2];
            float2 mv = *(const float2*)&mSh[kk][ty * 2];
            float2 zv = *(const float2*)&zSh[kk][tx * 2];
            float d;
            d = zv.x - mv.x; a00 += wv.x * d * d;
            d = zv.y - mv.x; a01 += wv.x * d * d;
            d = zv.x - mv.y; a10 += wv.y * d * d;
            d = zv.y - mv.y; a11 += wv.y * d * d;
        }
        __syncthreads();
    }
    int ii = i0 + ty * 2, jj = j0 + tx * 2;
    float accs[2][2] = {{a00, a01}, {a10, a11}};
    for (int a = 0; a < 2; ++a)
        for (int c = 0; c < 2; ++c) {
            int I = ii + a, J = jj + c;
            if (I < R && J < C)
                out[(size_t)b * R * pitch + (size_t)I * pitch + J] =
                    SLrow[b * R + I] - SLcol[b * C + J] - 0.5f * H_ + 0.5f * accs[a][c];
        }
}

// Fused: blocks 0..7 = soft-DTW wavefront (which = bid>>2, b = bid&3);
//        blocks 8..  = grid-stride elementwise reductions (float4).
__global__ __launch_bounds__(512) void main_kernel(
    const float* __restrict__ mel, const float* __restrict__ melh,
    const float* __restrict__ sg,  const float* __restrict__ se,
    const float* __restrict__ fr,  const float* __restrict__ ff,
    const float* __restrict__ dur, const float* __restrict__ pmask,
    const float* __restrict__ zmask, float* ws) {
    __shared__ float sbuf[3][416];
    __shared__ float qmLds[416];
    int bid = blockIdx.x, tid = threadIdx.x;
    if (bid < 8) {
        // ---------------- soft-DTW ----------------
        int b = bid & 3, which = bid >> 2;
        int R_, C_, pitch;
        const float* klbase; const float* rmask; const float* cmask;
        if (which == 0) {
            R_ = TP_; C_ = TQ_; pitch = KL1_PITCH;
            klbase = ws + KL1_OFF + (size_t)b * TP_ * KL1_PITCH;
            rmask = pmask + b * TP_;  cmask = zmask + b * TQ_;
        } else {
            R_ = TQ_; C_ = TP_; pitch = KL2_PITCH;
            klbase = ws + KL2_OFF + (size_t)b * TQ_ * KL2_PITCH;
            rmask = zmask + b * TQ_;  cmask = pmask + b * TP_;
        }
        int N = R_ + 1, M = C_ + 1;          // D is N x M; R-matrix (N+1)x(M+1)
        for (int c = tid; c <= C_; c += 512) qmLds[c] = (c < C_) ? cmask[c] : 0.f;
        if (tid == 0) { sbuf[0][0] = 0.f; sbuf[1][0] = BIGV; sbuf[1][1] = BIGV; }
        __syncthreads();

        int i = tid + 1;                     // fixed R-row per thread
        bool rowvalid = (i <= N);
        int r = i - 1;                       // D row
        bool pb = rowvalid && (r < R_) && (rmask[r < R_ ? r : 0] != 0.f);
        const float* klrow = klbase + (size_t)(r < R_ ? r : 0) * pitch;

        auto loadD = [&](int d) -> float {
            int j = d - i;
            if (!rowvalid || j < 1 || j > M) return 0.f;
            int c = j - 1;
            bool qb = (qmLds[c] != 0.f);
            if (pb) return qb ? klrow[c] : INFV;
            return qb ? INFV : 0.f;
        };

        float Dcur = loadD(2);
        int NM = N + M;
        int cur = 2, p1 = 1, p2 = 0;
        for (int d = 2; d <= NM; ++d) {
            float Dnext = loadD(d + 1);      // prefetch next diagonal's D
            if (tid == 0) {
                if (d <= M) sbuf[cur][0] = BIGV;   // R[0,d]
                if (d <= N) sbuf[cur][d] = BIGV;   // R[d,0]
            }
            int j = d - i;
            if (rowvalid && j >= 1 && j <= M) {
                float rd = sbuf[p2][i - 1];
                float ru = sbuf[p1][i - 1];
                float rl = sbuf[p1][i];
                float r0 = rd * -100.f;
                float r1 = (ru + WARP_) * -100.f;
                float r2 = (rl + WARP_) * -100.f;
                float mx = fmaxf(fmaxf(r0, r1), r2);
                float s  = __expf(r0 - mx) + __expf(r1 - mx) + __expf(r2 - mx);
                float smin = -GAMMA_ * (__logf(s) + mx);
                sbuf[cur][i] = Dcur + smin;
            }
            __syncthreads();
            Dcur = Dnext;
            int tmp = p2; p2 = p1; p1 = cur; cur = tmp;
        }
        if (tid == 0) ws[DTW_OFF + which * 4 + b] = sbuf[p1][N];
    } else {
        // ---------------- reductions ----------------
        int rid = bid - 8;
        long NR = (long)gridDim.x - 8;
        const float4* fr4   = (const float4*)fr;
        const float4* ff4   = (const float4*)ff;
        const float4* sg4   = (const float4*)sg;
        const float4* se4   = (const float4*)se;
        const float4* mel4  = (const float4*)mel;
        const float4* melh4 = (const float4*)melh;
        const float4* dur4  = (const float4*)dur;
        const float4* pm4   = (const float4*)pmask;
        const float4* zm4   = (const float4*)zmask;
        const long E0 = 12582912;       // feats (24*4*128*4096/4)
        const long E1 = E0 + 49152;     // gen   (6*4*8192/4)
        const long E2 = E1 + 49152;     // e2e
        const long E3 = E2 + 10240;     // mel   (4*80*128/4)
        const long E4 = E3 + 350;       // dur   (1400/4)
        const long E5 = E4 + 350;       // pm
        const long E6 = E5 + 400;       // qm    (1600/4)
        float a0=0.f,a1=0.f,a2=0.f,a3=0.f,a4=0.f,a5=0.f,a6=0.f;
        long stride = NR * 512;
        for (long v = (long)rid * 512 + tid; v < E6; v += stride) {
            if (v < E0) {
                float4 x = fr4[v], y = ff4[v];
                a2 += fabsf(x.x - y.x) + fabsf(x.y - y.y) + fabsf(x.z - y.z) + fabsf(x.w - y.w);
            } else if (v < E1) {
                float4 s = sg4[v - E0]; float e;
                e = 1.f - s.x; a0 += e * e; e = 1.f - s.y; a0 += e * e;
                e = 1.f - s.z; a0 += e * e; e = 1.f - s.w; a0 += e * e;
            } else if (v < E2) {
                float4 s = se4[v - E1]; float e;
                e = 1.f - s.x; a1 += e * e; e = 1.f - s.y; a1 += e * e;
                e = 1.f - s.z; a1 += e * e; e = 1.f - s.w; a1 += e * e;
            } else if (v < E3) {
                float4 x = mel4[v - E2], y = melh4[v - E2];
                a3 += fabsf(x.x - y.x) + fabsf(x.y - y.y) + fabsf(x.z - y.z) + fabsf(x.w - y.w);
            } else if (v < E4) {
                float4 x = dur4[v - E3]; a4 += x.x + x.y + x.z + x.w;
            } else if (v < E5) {
                float4 x = pm4[v - E4]; a5 += x.x + x.y + x.z + x.w;
            } else {
                float4 x = zm4[v - E5]; a6 += x.x + x.y + x.z + x.w;
            }
        }
        float vals[7] = {a0, a1, a2, a3, a4, a5, a6};
#pragma unroll
        for (int q = 0; q < 7; ++q) {
            float v = vals[q];
            for (int off = 32; off > 0; off >>= 1) v += __shfl_xor(v, off);
            if ((tid & 63) == 0) sbuf[0][(tid >> 6) * 8 + q] = v;
        }
        __syncthreads();
        if (tid < 7) {
            float s = 0.f;
            for (int w = 0; w < 8; ++w) s += sbuf[0][w * 8 + tid];
            atomicAdd(&ws[ACC_OFF + tid], s);
        }
    }
}

__global__ void final_kernel(const float* __restrict__ ws,
                             const float* __restrict__ ldl,
                             float* __restrict__ out) {
    if (threadIdx.x == 0 && blockIdx.x == 0) {
        float gen  = ws[0] * (1.f / 32768.f);
        float e2e  = ws[1] * (1.f / 32768.f);
        float fm   = ws[2] * (2.f / 2097152.f);
        float melv = ws[3] * (45.f / 40960.f);
        float durv = ws[4];
        float dlen = logf(ldl[0] + 1e-6f);
        float kl  = (ws[DTW_OFF + 0] + ws[DTW_OFF + 1] + ws[DTW_OFF + 2] + ws[DTW_OFF + 3]) / ws[5];
        float klf = (ws[DTW_OFF + 4] + ws[DTW_OFF + 5] + ws[DTW_OFF + 6] + ws[DTW_OFF + 7]) / ws[6];
        out[0] = gen + e2e + fm + melv + durv + dlen + kl + klf;
    }
}

extern "C" void kernel_launch(void* const* d_in, const int* in_sizes, int n_in,
                              void* d_out, int out_size, void* d_ws, size_t ws_size,
                              hipStream_t stream) {
    const float* mel    = (const float*)d_in[0];
    const float* melh   = (const float*)d_in[1];
    const float* sg     = (const float*)d_in[2];
    const float* se     = (const float*)d_in[3];
    const float* fr     = (const float*)d_in[4];
    const float* ff     = (const float*)d_in[5];
    const float* dur    = (const float*)d_in[6];
    const float* ldl    = (const float*)d_in[7];
    // d_in[8] = loss_pitch (unused by reference)
    const float* z_p    = (const float*)d_in[9];
    const float* m_p    = (const float*)d_in[10];
    const float* logs_p = (const float*)d_in[11];
    const float* z_q    = (const float*)d_in[12];
    const float* m_q    = (const float*)d_in[13];
    const float* logs_q = (const float*)d_in[14];
    const float* pmask  = (const float*)d_in[15];
    const float* zmask  = (const float*)d_in[16];  // (B,1,TQ) == flat (B,TQ)
    float* ws  = (float*)d_ws;
    float* out = (float*)d_out;

    zero_kernel<<<1, 64, 0, stream>>>(ws);
    sl_kernel<<<12, 256, 0, stream>>>(logs_p, logs_q, ws);
    // kl1: rows = m_p/logs_p (350), cols = z_p (400)
    kl_kernel<<<dim3(13, 11, B_), dim3(16, 16), 0, stream>>>(
        m_p, logs_p, z_p, ws + SLP_OFF, ws + SLQ_OFF, ws + KL1_OFF, TP_, TQ_, KL1_PITCH);
    // kl2: rows = m_q/logs_q (400), cols = z_q (350)
    kl_kernel<<<dim3(11, 13, B_), dim3(16, 16), 0, stream>>>(
        m_q, logs_q, z_q, ws + SLQ_OFF, ws + SLP_OFF, ws + KL2_OFF, TQ_, TP_, KL2_PITCH);
    main_kernel<<<8 + 1016, 512, 0, stream>>>(mel, melh, sg, se, fr, ff, dur, pmask, zmask, ws);
    final_kernel<<<1, 64, 0, stream>>>(ws, ldl, out);
}

// Round 2
// 534.049 us; speedup vs baseline: 1.2589x; 1.2589x over previous
//
#include <hip/hip_runtime.h>
#include <math.h>

// ---------------- problem constants ----------------
#define GAMMA_ 0.01f
#define WARP_  134.4f
#define INFV   100000.0f
#define BIGV   1000000000.0f

#define B_  4
#define H_  192
#define TP_ 350
#define TQ_ 400

// ---------------- workspace layout (float offsets) ----------------
// acc[0]=gen acc[1]=e2e acc[2]=fm acc[3]=mel acc[4]=dur acc[5]=sum_pm acc[6]=sum_qm
#define ACC_OFF 0
#define DTW_OFF 16                          // 8 results: [which*4 + b]
#define SLP_OFF 32                          // sum_h logs_p  [B][350]
#define SLQ_OFF (SLP_OFF + B_*TP_)          // sum_h logs_q  [B][400]
#define KL1_OFF 3072                        // klT1 [B][TQ_=400][352]  (transposed: [col j][row i])
#define KL1_PITCHT 352
#define KL2_OFF (KL1_OFF + B_*TQ_*KL1_PITCHT)   // klT2 [B][TP_=350][400]
#define KL2_PITCHT 400
// total = 3072 + 563200 + 560000 = 1,126,272 floats = 4,505,088 bytes

// per-position sums over h of logs_p / logs_q  (+ zero the accumulators)
__global__ void sl_kernel(const float* __restrict__ logs_p,
                          const float* __restrict__ logs_q,
                          float* __restrict__ ws) {
    int t = blockIdx.x * 256 + threadIdx.x;
    if (t < 32) ws[ACC_OFF + t] = 0.f;
    if (t < B_ * TP_) {
        int b = t / TP_, i = t % TP_;
        const float* p = logs_p + (size_t)b * H_ * TP_ + i;
        float s = 0.f;
        for (int h = 0; h < H_; ++h) s += p[(size_t)h * TP_];
        ws[SLP_OFF + t] = s;
    } else if (t < B_ * TP_ + B_ * TQ_) {
        int t2 = t - B_ * TP_;
        int b = t2 / TQ_, j = t2 % TQ_;
        const float* p = logs_q + (size_t)b * H_ * TQ_ + j;
        float s = 0.f;
        for (int h = 0; h < H_; ++h) s += p[(size_t)h * TQ_];
        ws[SLQ_OFF + t2] = s;
    }
}

// klT[b][J][I] = SLrow[b,I] - SLcol[b,J] - 0.5*H + 0.5 * sum_h w[h,I]*(z[h,J]-m[h,I])^2
// (transposed output: major dim = z-position J, minor = m-position I, coalesced over I)
// blockIdx.z: 0..3 = which0 batches, 4..7 = which1 batches.
__global__ void kl_kernel(const float* __restrict__ mp, const float* __restrict__ lsp,
                          const float* __restrict__ zp,
                          const float* __restrict__ mq, const float* __restrict__ lsq,
                          const float* __restrict__ zq,
                          float* __restrict__ ws) {
    int which = blockIdx.z >> 2;
    int b     = blockIdx.z & 3;
    const float *mS, *lS, *zS, *SLrow, *SLcol; float* out; int R, C, pitchT;
    if (which == 0) { mS=mp; lS=lsp; zS=zp; SLrow=ws+SLP_OFF; SLcol=ws+SLQ_OFF;
                      out=ws+KL1_OFF; R=TP_; C=TQ_; pitchT=KL1_PITCHT; }
    else            { mS=mq; lS=lsq; zS=zq; SLrow=ws+SLQ_OFF; SLcol=ws+SLP_OFF;
                      out=ws+KL2_OFF; R=TQ_; C=TP_; pitchT=KL2_PITCHT; }
    int i0 = blockIdx.x * 32;       // m-side (minor dim of klT)
    int j0 = blockIdx.y * 32;       // z-side (major dim of klT)
    if (i0 >= R || j0 >= C) return;
    __shared__ __align__(16) float wS [16][32];
    __shared__ __align__(16) float mSh[16][32];
    __shared__ __align__(16) float zSh[16][32];
    const float* mB = mS + (size_t)b * H_ * R;
    const float* lB = lS + (size_t)b * H_ * R;
    const float* zB = zS + (size_t)b * H_ * C;
    int tx = threadIdx.x, ty = threadIdx.y;    // tx -> i, ty -> j
    int t  = ty * 16 + tx;
    float a00 = 0.f, a01 = 0.f, a10 = 0.f, a11 = 0.f;  // a[jj][ii]
    for (int h0 = 0; h0 < H_; h0 += 16) {
        for (int e = t; e < 512; e += 256) {
            int hh = e >> 5, cc = e & 31;
            int h = h0 + hh;
            int gi = i0 + cc, gj = j0 + cc;
            float wv = 0.f, mv = 0.f;
            if (gi < R) {
                wv = __expf(-2.f * lB[(size_t)h * R + gi]);
                mv = mB[(size_t)h * R + gi];
            }
            wS[hh][cc] = wv; mSh[hh][cc] = mv;
            zSh[hh][cc] = (gj < C) ? zB[(size_t)h * C + gj] : 0.f;
        }
        __syncthreads();
#pragma unroll
        for (int kk = 0; kk < 16; ++kk) {
            float2 wv = *(const float2*)&wS [kk][tx * 2];
            float2 mv = *(const float2*)&mSh[kk][tx * 2];
            float2 zv = *(const float2*)&zSh[kk][ty * 2];
            float d;
            d = zv.x - mv.x; a00 += wv.x * d * d;
            d = zv.x - mv.y; a01 += wv.y * d * d;
            d = zv.y - mv.x; a10 += wv.x * d * d;
            d = zv.y - mv.y; a11 += wv.y * d * d;
        }
        __syncthreads();
    }
    float accs[2][2] = {{a00, a01}, {a10, a11}};
    for (int jj = 0; jj < 2; ++jj)
        for (int ii = 0; ii < 2; ++ii) {
            int I = i0 + tx * 2 + ii, J = j0 + ty * 2 + jj;
            if (I < R && J < C)
                out[((size_t)b * C + J) * pitchT + I] =
                    SLrow[b * R + I] - SLcol[b * C + J] - 0.5f * H_ + 0.5f * accs[jj][ii];
        }
}

// Fused: blocks 0..7 = barrier-free single-wave soft-DTW (which = bid>>2, b = bid&3);
//        blocks 8..  = grid-stride elementwise reductions (float4).
__global__ __launch_bounds__(512) void main_kernel(
    const float* __restrict__ mel, const float* __restrict__ melh,
    const float* __restrict__ sg,  const float* __restrict__ se,
    const float* __restrict__ fr,  const float* __restrict__ ff,
    const float* __restrict__ dur, const float* __restrict__ pmask,
    const float* __restrict__ zmask, float* ws) {
    __shared__ float qmLds[400];
    __shared__ float sbuf[64];
    int bid = blockIdx.x, tid = threadIdx.x;
    if (bid < 8) {
        // ---------------- soft-DTW, one wave, lane-skewed column sweep ----------------
        int b = bid & 3, which = bid >> 2;
        int R_, C_, pitchT;
        const float* klT; const float* rmask; const float* cmask;
        if (which == 0) {
            R_ = TP_; C_ = TQ_; pitchT = KL1_PITCHT;
            klT = ws + KL1_OFF + (size_t)b * TQ_ * KL1_PITCHT;
            rmask = pmask + b * TP_;  cmask = zmask + b * TQ_;
        } else {
            R_ = TQ_; C_ = TP_; pitchT = KL2_PITCHT;
            klT = ws + KL2_OFF + (size_t)b * TP_ * KL2_PITCHT;
            rmask = zmask + b * TQ_;  cmask = pmask + b * TP_;
        }
        for (int c = tid; c < C_; c += 512) qmLds[c] = cmask[c];
        __syncthreads();                 // all 512 threads reach this, then 448 exit
        if (tid >= 64) return;
        int lane = tid;
        const int RB = 7;
        int N = R_ + 1, M = C_ + 1;      // D is N x M; R-matrix (N+1)x(M+1); answer R[N][M]
        int r0 = lane * RB;              // first D-row owned by this lane
        int kmaxc = N - r0;  kmaxc = kmaxc < 0 ? 0 : (kmaxc > RB ? RB : kmaxc);   // valid R-rows
        int kload = R_ - r0; kload = kload < 0 ? 0 : (kload > RB ? RB : kload);   // rows with stored kl
        bool pb[RB];
#pragma unroll
        for (int k = 0; k < RB; ++k) pb[k] = (k < kload) ? (rmask[r0 + k] != 0.f) : false;
        float prevcol[RB], dsel[RB];
#pragma unroll
        for (int k = 0; k < RB; ++k) { prevcol[k] = BIGV; dsel[k] = 0.f; }
        float recv_cur = BIGV, recv_prev = BIGV;
        int lres = (N - 1) / RB;
        int kres = N - (lres * RB + 1);
        int tmax = M + lres;
        // prefetch + select for step t=1 (column c = -lane; only lane 0 real)
        {
            int cn = -lane;
            bool qbn = false;
            float dnext[RB];
#pragma unroll
            for (int k = 0; k < RB; ++k) dnext[k] = 0.f;
            if (cn >= 0 && cn < M) {
                qbn = (cn < C_) ? (qmLds[cn] != 0.f) : false;
                if (qbn) {
                    const float* col = klT + (size_t)cn * pitchT + r0;
#pragma unroll
                    for (int k = 0; k < RB; ++k) if (k < kload) dnext[k] = col[k];
                }
            }
#pragma unroll
            for (int k = 0; k < RB; ++k)
                dsel[k] = pb[k] ? (qbn ? dnext[k] : INFV) : (qbn ? INFV : 0.f);
        }
        for (int t = 1; t <= tmax; ++t) {
            int j = t - lane;
            // ---- prefetch for step t+1 (issue loads before the compute chain) ----
            int cn = t - lane;
            bool qbn = false;
            float dnext[RB];
#pragma unroll
            for (int k = 0; k < RB; ++k) dnext[k] = 0.f;
            if (cn >= 0 && cn < M) {
                qbn = (cn < C_) ? (qmLds[cn] != 0.f) : false;
                if (qbn) {
                    const float* col = klT + (size_t)cn * pitchT + r0;
#pragma unroll
                    for (int k = 0; k < RB; ++k) if (k < kload) dnext[k] = col[k];
                }
            }
            // ---- compute this lane's 7-row chunk for column j ----
            float last = 0.f;
            if (j >= 1 && j <= M && kmaxc > 0) {
                float up   = (lane == 0) ? BIGV : recv_cur;                  // R[r0][j]
                float diag = (j == 1) ? ((lane == 0) ? 0.f : BIGV)
                                      : ((lane == 0) ? BIGV : recv_prev);    // R[r0][j-1]
#pragma unroll
                for (int k = 0; k < RB; ++k) {
                    if (k < kmaxc) {
                        float rl  = prevcol[k];
                        float rr0 = diag * -100.f;
                        float rr1 = (up + WARP_) * -100.f;
                        float rr2 = (rl + WARP_) * -100.f;
                        float mx  = fmaxf(fmaxf(rr0, rr1), rr2);
                        float s   = __expf(rr0 - mx) + __expf(rr1 - mx) + __expf(rr2 - mx);
                        float val = dsel[k] - GAMMA_ * (__logf(s) + mx);
                        diag = rl; up = val; prevcol[k] = val;
                    }
                }
                last = up;
            }
            // ---- pipeline hand-off (all lanes) ----
            recv_prev = recv_cur;
            recv_cur  = __shfl_up(last, 1u);
            // ---- commit prefetch into dsel with mask logic ----
#pragma unroll
            for (int k = 0; k < RB; ++k)
                dsel[k] = pb[k] ? (qbn ? dnext[k] : INFV) : (qbn ? INFV : 0.f);
        }
        float myres = 0.f;
#pragma unroll
        for (int k = 0; k < RB; ++k) if (k == kres) myres = prevcol[k];
        float res = __shfl(myres, lres);
        if (lane == 0) ws[DTW_OFF + which * 4 + b] = res;
    } else {
        // ---------------- reductions ----------------
        int rid = bid - 8;
        long NR = (long)gridDim.x - 8;
        const float4* fr4   = (const float4*)fr;
        const float4* ff4   = (const float4*)ff;
        const float4* sg4   = (const float4*)sg;
        const float4* se4   = (const float4*)se;
        const float4* mel4  = (const float4*)mel;
        const float4* melh4 = (const float4*)melh;
        const float4* dur4  = (const float4*)dur;
        const float4* pm4   = (const float4*)pmask;
        const float4* zm4   = (const float4*)zmask;
        const long E0 = 12582912;       // feats (24*4*128*4096/4)
        const long E1 = E0 + 49152;     // gen   (6*4*8192/4)
        const long E2 = E1 + 49152;     // e2e
        const long E3 = E2 + 10240;     // mel   (4*80*128/4)
        const long E4 = E3 + 350;       // dur   (1400/4)
        const long E5 = E4 + 350;       // pm
        const long E6 = E5 + 400;       // qm    (1600/4)
        float a0=0.f,a1=0.f,a2=0.f,a3=0.f,a4=0.f,a5=0.f,a6=0.f;
        long stride = NR * 512;
        for (long v = (long)rid * 512 + tid; v < E6; v += stride) {
            if (v < E0) {
                float4 x = fr4[v], y = ff4[v];
                a2 += fabsf(x.x - y.x) + fabsf(x.y - y.y) + fabsf(x.z - y.z) + fabsf(x.w - y.w);
            } else if (v < E1) {
                float4 s = sg4[v - E0]; float e;
                e = 1.f - s.x; a0 += e * e; e = 1.f - s.y; a0 += e * e;
                e = 1.f - s.z; a0 += e * e; e = 1.f - s.w; a0 += e * e;
            } else if (v < E2) {
                float4 s = se4[v - E1]; float e;
                e = 1.f - s.x; a1 += e * e; e = 1.f - s.y; a1 += e * e;
                e = 1.f - s.z; a1 += e * e; e = 1.f - s.w; a1 += e * e;
            } else if (v < E3) {
                float4 x = mel4[v - E2], y = melh4[v - E2];
                a3 += fabsf(x.x - y.x) + fabsf(x.y - y.y) + fabsf(x.z - y.z) + fabsf(x.w - y.w);
            } else if (v < E4) {
                float4 x = dur4[v - E3]; a4 += x.x + x.y + x.z + x.w;
            } else if (v < E5) {
                float4 x = pm4[v - E4]; a5 += x.x + x.y + x.z + x.w;
            } else {
                float4 x = zm4[v - E5]; a6 += x.x + x.y + x.z + x.w;
            }
        }
        float vals[7] = {a0, a1, a2, a3, a4, a5, a6};
#pragma unroll
        for (int q = 0; q < 7; ++q) {
            float v = vals[q];
            for (int off = 32; off > 0; off >>= 1) v += __shfl_xor(v, off);
            if ((tid & 63) == 0) sbuf[(tid >> 6) * 8 + q] = v;
        }
        __syncthreads();
        if (tid < 7) {
            float s = 0.f;
            for (int w = 0; w < 8; ++w) s += sbuf[w * 8 + tid];
            atomicAdd(&ws[ACC_OFF + tid], s);
        }
    }
}

__global__ void final_kernel(const float* __restrict__ ws,
                             const float* __restrict__ ldl,
                             float* __restrict__ out) {
    if (threadIdx.x == 0 && blockIdx.x == 0) {
        float gen  = ws[0] * (1.f / 32768.f);
        float e2e  = ws[1] * (1.f / 32768.f);
        float fm   = ws[2] * (2.f / 2097152.f);
        float melv = ws[3] * (45.f / 40960.f);
        float durv = ws[4];
        float dlen = logf(ldl[0] + 1e-6f);
        float kl  = (ws[DTW_OFF + 0] + ws[DTW_OFF + 1] + ws[DTW_OFF + 2] + ws[DTW_OFF + 3]) / ws[5];
        float klf = (ws[DTW_OFF + 4] + ws[DTW_OFF + 5] + ws[DTW_OFF + 6] + ws[DTW_OFF + 7]) / ws[6];
        out[0] = gen + e2e + fm + melv + durv + dlen + kl + klf;
    }
}

extern "C" void kernel_launch(void* const* d_in, const int* in_sizes, int n_in,
                              void* d_out, int out_size, void* d_ws, size_t ws_size,
                              hipStream_t stream) {
    const float* mel    = (const float*)d_in[0];
    const float* melh   = (const float*)d_in[1];
    const float* sg     = (const float*)d_in[2];
    const float* se     = (const float*)d_in[3];
    const float* fr     = (const float*)d_in[4];
    const float* ff     = (const float*)d_in[5];
    const float* dur    = (const float*)d_in[6];
    const float* ldl    = (const float*)d_in[7];
    // d_in[8] = loss_pitch (unused by reference)
    const float* z_p    = (const float*)d_in[9];
    const float* m_p    = (const float*)d_in[10];
    const float* logs_p = (const float*)d_in[11];
    const float* z_q    = (const float*)d_in[12];
    const float* m_q    = (const float*)d_in[13];
    const float* logs_q = (const float*)d_in[14];
    const float* pmask  = (const float*)d_in[15];
    const float* zmask  = (const float*)d_in[16];  // (B,1,TQ) == flat (B,TQ)
    float* ws  = (float*)d_ws;
    float* out = (float*)d_out;

    sl_kernel<<<12, 256, 0, stream>>>(logs_p, logs_q, ws);
    kl_kernel<<<dim3(13, 13, 8), dim3(16, 16), 0, stream>>>(
        m_p, logs_p, z_p, m_q, logs_q, z_q, ws);
    main_kernel<<<8 + 1016, 512, 0, stream>>>(mel, melh, sg, se, fr, ff, dur, pmask, zmask, ws);
    final_kernel<<<1, 64, 0, stream>>>(ws, ldl, out);
}

// Round 3
// 386.133 us; speedup vs baseline: 1.7412x; 1.3831x over previous
//
#include <hip/hip_runtime.h>
#include <math.h>

// ---------------- problem constants ----------------
#define GAMMA_ 0.01f
#define WARP_  134.4f
#define INFV   100000.0f
#define BIGV   1000000000.0f

#define B_  4
#define H_  192
#define TP_ 350
#define TQ_ 400

// ---------------- workspace layout (float offsets) ----------------
// acc[0]=gen acc[1]=e2e acc[2]=fm acc[3]=mel acc[4]=dur acc[5]=sum_pm acc[6]=sum_qm
#define ACC_OFF 0
#define DTW_OFF 16                          // 8 results: [which*4 + b]
#define SLP_OFF 32                          // sum_h logs_p  [B][350]
#define SLQ_OFF (SLP_OFF + B_*TP_)          // sum_h logs_q  [B][400]
#define KL1_OFF 3072                        // klT1 [B][TQ_=400][352]  (transposed: [col j][row i])
#define KL1_PITCHT 352
#define KL2_OFF (KL1_OFF + B_*TQ_*KL1_PITCHT)   // klT2 [B][TP_=350][400]
#define KL2_PITCHT 400
// total = 3072 + 563200 + 560000 = 1,126,272 floats = 4,505,088 bytes

// per-position sums over h of logs_p / logs_q  (+ zero the accumulators)
__global__ void sl_kernel(const float* __restrict__ logs_p,
                          const float* __restrict__ logs_q,
                          float* __restrict__ ws) {
    int t = blockIdx.x * 256 + threadIdx.x;
    if (t < 32) ws[ACC_OFF + t] = 0.f;
    if (t < B_ * TP_) {
        int b = t / TP_, i = t % TP_;
        const float* p = logs_p + (size_t)b * H_ * TP_ + i;
        float s = 0.f;
        for (int h = 0; h < H_; ++h) s += p[(size_t)h * TP_];
        ws[SLP_OFF + t] = s;
    } else if (t < B_ * TP_ + B_ * TQ_) {
        int t2 = t - B_ * TP_;
        int b = t2 / TQ_, j = t2 % TQ_;
        const float* p = logs_q + (size_t)b * H_ * TQ_ + j;
        float s = 0.f;
        for (int h = 0; h < H_; ++h) s += p[(size_t)h * TQ_];
        ws[SLQ_OFF + t2] = s;
    }
}

// klT[b][J][I] = SLrow[b,I] - SLcol[b,J] - 0.5*H + 0.5 * sum_h w[h,I]*(z[h,J]-m[h,I])^2
__global__ void kl_kernel(const float* __restrict__ mp, const float* __restrict__ lsp,
                          const float* __restrict__ zp,
                          const float* __restrict__ mq, const float* __restrict__ lsq,
                          const float* __restrict__ zq,
                          float* __restrict__ ws) {
    int which = blockIdx.z >> 2;
    int b     = blockIdx.z & 3;
    const float *mS, *lS, *zS, *SLrow, *SLcol; float* out; int R, C, pitchT;
    if (which == 0) { mS=mp; lS=lsp; zS=zp; SLrow=ws+SLP_OFF; SLcol=ws+SLQ_OFF;
                      out=ws+KL1_OFF; R=TP_; C=TQ_; pitchT=KL1_PITCHT; }
    else            { mS=mq; lS=lsq; zS=zq; SLrow=ws+SLQ_OFF; SLcol=ws+SLP_OFF;
                      out=ws+KL2_OFF; R=TQ_; C=TP_; pitchT=KL2_PITCHT; }
    int i0 = blockIdx.x * 32;       // m-side (minor dim of klT)
    int j0 = blockIdx.y * 32;       // z-side (major dim of klT)
    if (i0 >= R || j0 >= C) return;
    __shared__ __align__(16) float wS [16][32];
    __shared__ __align__(16) float mSh[16][32];
    __shared__ __align__(16) float zSh[16][32];
    const float* mB = mS + (size_t)b * H_ * R;
    const float* lB = lS + (size_t)b * H_ * R;
    const float* zB = zS + (size_t)b * H_ * C;
    int tx = threadIdx.x, ty = threadIdx.y;    // tx -> i, ty -> j
    int t  = ty * 16 + tx;
    float a00 = 0.f, a01 = 0.f, a10 = 0.f, a11 = 0.f;  // a[jj][ii]
    for (int h0 = 0; h0 < H_; h0 += 16) {
        for (int e = t; e < 512; e += 256) {
            int hh = e >> 5, cc = e & 31;
            int h = h0 + hh;
            int gi = i0 + cc, gj = j0 + cc;
            float wv = 0.f, mv = 0.f;
            if (gi < R) {
                wv = __expf(-2.f * lB[(size_t)h * R + gi]);
                mv = mB[(size_t)h * R + gi];
            }
            wS[hh][cc] = wv; mSh[hh][cc] = mv;
            zSh[hh][cc] = (gj < C) ? zB[(size_t)h * C + gj] : 0.f;
        }
        __syncthreads();
#pragma unroll
        for (int kk = 0; kk < 16; ++kk) {
            float2 wv = *(const float2*)&wS [kk][tx * 2];
            float2 mv = *(const float2*)&mSh[kk][tx * 2];
            float2 zv = *(const float2*)&zSh[kk][ty * 2];
            float d;
            d = zv.x - mv.x; a00 += wv.x * d * d;
            d = zv.x - mv.y; a01 += wv.y * d * d;
            d = zv.y - mv.x; a10 += wv.x * d * d;
            d = zv.y - mv.y; a11 += wv.y * d * d;
        }
        __syncthreads();
    }
    float accs[2][2] = {{a00, a01}, {a10, a11}};
    for (int jj = 0; jj < 2; ++jj)
        for (int ii = 0; ii < 2; ++ii) {
            int I = i0 + tx * 2 + ii, J = j0 + ty * 2 + jj;
            if (I < R && J < C)
                out[((size_t)b * C + J) * pitchT + I] =
                    SLrow[b * R + I] - SLcol[b * C + J] - 0.5f * H_ + 0.5f * accs[jj][ii];
        }
}

// ---------------- DTW step macros (named registers only, no arrays) ----------------
#define ISSUE(BK, TC) { \
    int c2_ = (TC) + 1 - lane; \
    bool ok_ = ((unsigned)c2_ < (unsigned)C_); \
    qv##BK = ok_ ? cmask[c2_] : 0.f; \
    if (ok_ & rvalid) { \
        const float* cp_ = klL + (long)c2_ * pitchT; \
        dn##BK##0 = cp_[0]; dn##BK##1 = cp_[1]; dn##BK##2 = cp_[2]; \
        dn##BK##3 = cp_[3]; dn##BK##4 = cp_[4]; dn##BK##5 = cp_[5]; dn##BK##6 = cp_[6]; \
    } \
}

#define COMMIT(BK) { \
    bool qb_ = (qv##BK != 0.f); \
    float dd0_ = sh0 ? dn##BK##0 : dn##BK##6; \
    ds0 = qb_ ? (pb0 ? dd0_       : INFV) : bb0; \
    ds1 = qb_ ? (pb1 ? dn##BK##1 : INFV) : bb1; \
    ds2 = qb_ ? (pb2 ? dn##BK##2 : INFV) : bb2; \
    ds3 = qb_ ? (pb3 ? dn##BK##3 : INFV) : bb3; \
    ds4 = qb_ ? (pb4 ? dn##BK##4 : INFV) : bb4; \
    ds5 = qb_ ? (pb5 ? dn##BK##5 : INFV) : bb5; \
    ds6 = qb_ ? (pb6 ? dn##BK##6 : INFV) : bb6; \
}

#define CELL(k) { float mn_ = fminf(fminf(diag, up + WARP_), p##k + WARP_); \
                  float v_ = ds##k + mn_; diag = p##k; up = v_; p##k = v_; }

#define COMPUTE(TC) { \
    int j_ = (TC) - lane; \
    float last_ = 0.f; \
    if (j_ >= 1 && j_ <= M) { \
        float up   = (lane == 0) ? BIGV : recv_cur; \
        float diag = (j_ == 1) ? ((lane == 0) ? 0.f : BIGV) \
                               : ((lane == 0) ? BIGV : recv_prev); \
        CELL(0); CELL(1); CELL(2); CELL(3); CELL(4); CELL(5); CELL(6); \
        last_ = up; \
    } \
    recv_prev = recv_cur; \
    recv_cur  = __shfl_up(last_, 1); \
}

// Fused: blocks 0..7 = barrier-free single-wave soft-DTW (min3 softmin, reg-pipelined);
//        blocks 8..  = grid-stride elementwise reductions (float4).
__global__ __launch_bounds__(512) void main_kernel(
    const float* __restrict__ mel, const float* __restrict__ melh,
    const float* __restrict__ sg,  const float* __restrict__ se,
    const float* __restrict__ fr,  const float* __restrict__ ff,
    const float* __restrict__ dur, const float* __restrict__ pmask,
    const float* __restrict__ zmask, float* ws) {
    __shared__ float sbuf[64];
    int bid = blockIdx.x, tid = threadIdx.x;
    if (bid < 8) {
        if (tid >= 64) return;
        int lane = tid;
        int b = bid & 3, which = bid >> 2;
        int R_, C_, pitchT;
        const float* klT; const float* rmask; const float* cmask;
        if (which == 0) {
            R_ = TP_; C_ = TQ_; pitchT = KL1_PITCHT;
            klT = ws + KL1_OFF + (size_t)b * TQ_ * KL1_PITCHT;
            rmask = pmask + b * TP_;  cmask = zmask + b * TQ_;
        } else {
            R_ = TQ_; C_ = TP_; pitchT = KL2_PITCHT;
            klT = ws + KL2_OFF + (size_t)b * TP_ * KL2_PITCHT;
            rmask = zmask + b * TQ_;  cmask = pmask + b * TP_;
        }
        const int RB = 7;
        int N = R_ + 1, M = C_ + 1;          // D is N x M; answer = R[N][M]
        int r0 = lane * RB;
        bool rvalid = (r0 < R_);
        int r0L = (r0 < R_ - RB) ? r0 : (R_ - RB);
        bool sh0 = (r0 == r0L);
        const float* klL = klT + r0L;
        // per-row masks (static over the sweep)
        bool pb0,pb1,pb2,pb3,pb4,pb5,pb6; float bb0,bb1,bb2,bb3,bb4,bb5,bb6;
#define PBI(k) { int rr_ = r0 + k; bool t_ = (rr_ < R_) && (rmask[rr_ < R_ ? rr_ : 0] != 0.f); \
                 pb##k = t_; bb##k = t_ ? INFV : 0.f; }
        PBI(0) PBI(1) PBI(2) PBI(3) PBI(4) PBI(5) PBI(6)
#undef PBI
        float p0=BIGV,p1=BIGV,p2=BIGV,p3=BIGV,p4=BIGV,p5=BIGV,p6=BIGV;
        float ds0=0,ds1=0,ds2=0,ds3=0,ds4=0,ds5=0,ds6=0;
        float dnA0=0,dnA1=0,dnA2=0,dnA3=0,dnA4=0,dnA5=0,dnA6=0,qvA=0;
        float dnB0=0,dnB1=0,dnB2=0,dnB3=0,dnB4=0,dnB5=0,dnB6=0,qvB=0;
        float recv_cur = BIGV, recv_prev = BIGV;
        int lres = (N - 1) / RB;
        int kres = (N - 1) - lres * RB;
        int tmax = M + lres;
        int tmaxE = tmax + (tmax & 1);       // pad to even (extra step is guarded no-op)
        // prologue: ds <- column (-lane) [step 1]; bank B <- column (1-lane) [step 2]
        ISSUE(A, -1) COMMIT(A)
        ISSUE(B, 0)
        for (int t = 1; t <= tmaxE; t += 2) {
            ISSUE(A, t)     COMPUTE(t)     COMMIT(B)
            ISSUE(B, t + 1) COMPUTE(t + 1) COMMIT(A)
        }
        float q0 = __shfl(p0, lres), q1 = __shfl(p1, lres), q2 = __shfl(p2, lres),
              q3 = __shfl(p3, lres), q4 = __shfl(p4, lres), q5 = __shfl(p5, lres),
              q6 = __shfl(p6, lres);
        if (lane == 0) {
            float res = (kres == 0) ? q0 : (kres == 1) ? q1 : (kres == 2) ? q2 :
                        (kres == 3) ? q3 : (kres == 4) ? q4 : (kres == 5) ? q5 : q6;
            ws[DTW_OFF + which * 4 + b] = res;
        }
    } else {
        // ---------------- reductions ----------------
        int rid = bid - 8;
        long NR = (long)gridDim.x - 8;
        const float4* fr4   = (const float4*)fr;
        const float4* ff4   = (const float4*)ff;
        const float4* sg4   = (const float4*)sg;
        const float4* se4   = (const float4*)se;
        const float4* mel4  = (const float4*)mel;
        const float4* melh4 = (const float4*)melh;
        const float4* dur4  = (const float4*)dur;
        const float4* pm4   = (const float4*)pmask;
        const float4* zm4   = (const float4*)zmask;
        const long E0 = 12582912;       // feats (24*4*128*4096/4)
        const long E1 = E0 + 49152;     // gen   (6*4*8192/4)
        const long E2 = E1 + 49152;     // e2e
        const long E3 = E2 + 10240;     // mel   (4*80*128/4)
        const long E4 = E3 + 350;       // dur   (1400/4)
        const long E5 = E4 + 350;       // pm
        const long E6 = E5 + 400;       // qm    (1600/4)
        float a0=0.f,a1=0.f,a2=0.f,a3=0.f,a4=0.f,a5=0.f,a6=0.f;
        long stride = NR * 512;
        for (long v = (long)rid * 512 + tid; v < E6; v += stride) {
            if (v < E0) {
                float4 x = fr4[v], y = ff4[v];
                a2 += fabsf(x.x - y.x) + fabsf(x.y - y.y) + fabsf(x.z - y.z) + fabsf(x.w - y.w);
            } else if (v < E1) {
                float4 s = sg4[v - E0]; float e;
                e = 1.f - s.x; a0 += e * e; e = 1.f - s.y; a0 += e * e;
                e = 1.f - s.z; a0 += e * e; e = 1.f - s.w; a0 += e * e;
            } else if (v < E2) {
                float4 s = se4[v - E1]; float e;
                e = 1.f - s.x; a1 += e * e; e = 1.f - s.y; a1 += e * e;
                e = 1.f - s.z; a1 += e * e; e = 1.f - s.w; a1 += e * e;
            } else if (v < E3) {
                float4 x = mel4[v - E2], y = melh4[v - E2];
                a3 += fabsf(x.x - y.x) + fabsf(x.y - y.y) + fabsf(x.z - y.z) + fabsf(x.w - y.w);
            } else if (v < E4) {
                float4 x = dur4[v - E3]; a4 += x.x + x.y + x.z + x.w;
            } else if (v < E5) {
                float4 x = pm4[v - E4]; a5 += x.x + x.y + x.z + x.w;
            } else {
                float4 x = zm4[v - E5]; a6 += x.x + x.y + x.z + x.w;
            }
        }
        float vals[7] = {a0, a1, a2, a3, a4, a5, a6};
#pragma unroll
        for (int q = 0; q < 7; ++q) {
            float v = vals[q];
            for (int off = 32; off > 0; off >>= 1) v += __shfl_xor(v, off);
            if ((tid & 63) == 0) sbuf[(tid >> 6) * 8 + q] = v;
        }
        __syncthreads();
        if (tid < 7) {
            float s = 0.f;
            for (int w = 0; w < 8; ++w) s += sbuf[w * 8 + tid];
            atomicAdd(&ws[ACC_OFF + tid], s);
        }
    }
}

__global__ void final_kernel(const float* __restrict__ ws,
                             const float* __restrict__ ldl,
                             float* __restrict__ out) {
    if (threadIdx.x == 0 && blockIdx.x == 0) {
        float gen  = ws[0] * (1.f / 32768.f);
        float e2e  = ws[1] * (1.f / 32768.f);
        float fm   = ws[2] * (2.f / 2097152.f);
        float melv = ws[3] * (45.f / 40960.f);
        float durv = ws[4];
        float dlen = logf(ldl[0] + 1e-6f);
        float kl  = (ws[DTW_OFF + 0] + ws[DTW_OFF + 1] + ws[DTW_OFF + 2] + ws[DTW_OFF + 3]) / ws[5];
        float klf = (ws[DTW_OFF + 4] + ws[DTW_OFF + 5] + ws[DTW_OFF + 6] + ws[DTW_OFF + 7]) / ws[6];
        out[0] = gen + e2e + fm + melv + durv + dlen + kl + klf;
    }
}

extern "C" void kernel_launch(void* const* d_in, const int* in_sizes, int n_in,
                              void* d_out, int out_size, void* d_ws, size_t ws_size,
                              hipStream_t stream) {
    const float* mel    = (const float*)d_in[0];
    const float* melh   = (const float*)d_in[1];
    const float* sg     = (const float*)d_in[2];
    const float* se     = (const float*)d_in[3];
    const float* fr     = (const float*)d_in[4];
    const float* ff     = (const float*)d_in[5];
    const float* dur    = (const float*)d_in[6];
    const float* ldl    = (const float*)d_in[7];
    // d_in[8] = loss_pitch (unused by reference)
    const float* z_p    = (const float*)d_in[9];
    const float* m_p    = (const float*)d_in[10];
    const float* logs_p = (const float*)d_in[11];
    const float* z_q    = (const float*)d_in[12];
    const float* m_q    = (const float*)d_in[13];
    const float* logs_q = (const float*)d_in[14];
    const float* pmask  = (const float*)d_in[15];
    const float* zmask  = (const float*)d_in[16];  // (B,1,TQ) == flat (B,TQ)
    float* ws  = (float*)d_ws;
    float* out = (float*)d_out;

    sl_kernel<<<12, 256, 0, stream>>>(logs_p, logs_q, ws);
    kl_kernel<<<dim3(13, 13, 8), dim3(16, 16), 0, stream>>>(
        m_p, logs_p, z_p, m_q, logs_q, z_q, ws);
    main_kernel<<<8 + 1016, 512, 0, stream>>>(mel, melh, sg, se, fr, ff, dur, pmask, zmask, ws);
    final_kernel<<<1, 64, 0, stream>>>(ws, ldl, out);
}

// Round 4
// 378.224 us; speedup vs baseline: 1.7776x; 1.0209x over previous
//
#include <hip/hip_runtime.h>
#include <math.h>

// ---------------- problem constants ----------------
#define GAMMA_ 0.01f
#define WARP_  134.4f
#define INFV   100000.0f
#define BIGV   1000000000.0f

#define B_  4
#define H_  192
#define TP_ 350
#define TQ_ 400

// ---------------- workspace layout (float offsets) ----------------
// acc[0]=gen acc[1]=e2e acc[2]=fm acc[3]=mel acc[4]=dur acc[5]=sum_pm acc[6]=sum_qm
#define ACC_OFF 0
#define DTW_OFF 16                          // 8 results: [which*4 + b]
#define SLP_OFF 32                          // sum_h logs_p  [B][350]
#define SLQ_OFF (SLP_OFF + B_*TP_)          // sum_h logs_q  [B][400]
// D-matrices with masks BAKED IN (incl. pad row/col):
// klT1 [B][401 cols][pitch 352]  (col-major over D: [J][I], I=0..350)
#define KL1_OFF 3072
#define KL1_NCOL 401
#define KL1_PITCHT 352
// klT2 [B][351 cols][pitch 402]  (I=0..400)
#define KL2_OFF (KL1_OFF + B_*KL1_NCOL*KL1_PITCHT)
#define KL2_NCOL 351
#define KL2_PITCHT 402
// end = 3072 + 564608 + 564408 = 1,132,088 floats (+64 slack) ≈ 4.53 MB

// per-position sums over h of logs_p / logs_q  (+ zero the accumulators)
__global__ void sl_kernel(const float* __restrict__ logs_p,
                          const float* __restrict__ logs_q,
                          float* __restrict__ ws) {
    int t = blockIdx.x * 256 + threadIdx.x;
    if (t < 32) ws[ACC_OFF + t] = 0.f;
    if (t < B_ * TP_) {
        int b = t / TP_, i = t % TP_;
        const float* p = logs_p + (size_t)b * H_ * TP_ + i;
        float s = 0.f;
        for (int h = 0; h < H_; ++h) s += p[(size_t)h * TP_];
        ws[SLP_OFF + t] = s;
    } else if (t < B_ * TP_ + B_ * TQ_) {
        int t2 = t - B_ * TP_;
        int b = t2 / TQ_, j = t2 % TQ_;
        const float* p = logs_q + (size_t)b * H_ * TQ_ + j;
        float s = 0.f;
        for (int h = 0; h < H_; ++h) s += p[(size_t)h * TQ_];
        ws[SLQ_OFF + t2] = s;
    }
}

// Writes the fully-masked D matrix (transposed, [J][I]) including pad row I=R and
// pad col J=C:  D = (pb&&qb) ? kl : (pb^qb ? INF : 0),  pb/qb false on pads.
__global__ void kl_kernel(const float* __restrict__ mp, const float* __restrict__ lsp,
                          const float* __restrict__ zp,
                          const float* __restrict__ mq, const float* __restrict__ lsq,
                          const float* __restrict__ zq,
                          const float* __restrict__ pmask, const float* __restrict__ zmask,
                          float* __restrict__ ws) {
    int which = blockIdx.z >> 2;
    int b     = blockIdx.z & 3;
    const float *mS, *lS, *zS, *SLrow, *SLcol, *rm, *cm; float* out; int R, C, pitchT;
    if (which == 0) { mS=mp; lS=lsp; zS=zp; SLrow=ws+SLP_OFF; SLcol=ws+SLQ_OFF;
                      rm=pmask + b*TP_; cm=zmask + b*TQ_;
                      out=ws+KL1_OFF + (size_t)b*KL1_NCOL*KL1_PITCHT;
                      R=TP_; C=TQ_; pitchT=KL1_PITCHT; }
    else            { mS=mq; lS=lsq; zS=zq; SLrow=ws+SLQ_OFF; SLcol=ws+SLP_OFF;
                      rm=zmask + b*TQ_; cm=pmask + b*TP_;
                      out=ws+KL2_OFF + (size_t)b*KL2_NCOL*KL2_PITCHT;
                      R=TQ_; C=TP_; pitchT=KL2_PITCHT; }
    int i0 = blockIdx.x * 32;       // I (m-side, minor dim of klT), range [0, R]
    int j0 = blockIdx.y * 32;       // J (z-side, major dim of klT), range [0, C]
    if (i0 > R || j0 > C) return;
    __shared__ __align__(16) float wS [16][32];
    __shared__ __align__(16) float mSh[16][32];
    __shared__ __align__(16) float zSh[16][32];
    const float* mB = mS + (size_t)b * H_ * R;
    const float* lB = lS + (size_t)b * H_ * R;
    const float* zB = zS + (size_t)b * H_ * C;
    int tx = threadIdx.x, ty = threadIdx.y;    // tx -> i, ty -> j
    int t  = ty * 16 + tx;
    float a00 = 0.f, a01 = 0.f, a10 = 0.f, a11 = 0.f;  // a[jj][ii]
    for (int h0 = 0; h0 < H_; h0 += 16) {
        for (int e = t; e < 512; e += 256) {
            int hh = e >> 5, cc = e & 31;
            int h = h0 + hh;
            int gi = i0 + cc, gj = j0 + cc;
            float wv = 0.f, mv = 0.f;
            if (gi < R) {
                wv = __expf(-2.f * lB[(size_t)h * R + gi]);
                mv = mB[(size_t)h * R + gi];
            }
            wS[hh][cc] = wv; mSh[hh][cc] = mv;
            zSh[hh][cc] = (gj < C) ? zB[(size_t)h * C + gj] : 0.f;
        }
        __syncthreads();
#pragma unroll
        for (int kk = 0; kk < 16; ++kk) {
            float2 wv = *(const float2*)&wS [kk][tx * 2];
            float2 mv = *(const float2*)&mSh[kk][tx * 2];
            float2 zv = *(const float2*)&zSh[kk][ty * 2];
            float d;
            d = zv.x - mv.x; a00 += wv.x * d * d;
            d = zv.x - mv.y; a01 += wv.y * d * d;
            d = zv.y - mv.x; a10 += wv.x * d * d;
            d = zv.y - mv.y; a11 += wv.y * d * d;
        }
        __syncthreads();
    }
    float accs[2][2] = {{a00, a01}, {a10, a11}};
    for (int jj = 0; jj < 2; ++jj)
        for (int ii = 0; ii < 2; ++ii) {
            int I = i0 + tx * 2 + ii, J = j0 + ty * 2 + jj;
            if (I <= R && J <= C) {
                bool pbI = (I < R) && (rm[I] != 0.f);
                bool qbJ = (J < C) && (cm[J] != 0.f);
                float v;
                if (pbI & qbJ)
                    v = SLrow[b * R + I] - SLcol[b * C + J] - 0.5f * H_ + 0.5f * accs[jj][ii];
                else
                    v = (pbI ^ qbJ) ? INFV : 0.f;
                out[(size_t)J * pitchT + I] = v;
            }
        }
}

// ---------------- DTW macros (named registers only) ----------------
// ISSUE(bank, S): load D-column (S - lane) into bank (7 contiguous floats at rows r0..r0+6)
#define ISSUE(BK, S) { \
    int c_ = (S) - lane; \
    if (rvalid & ((unsigned)c_ <= (unsigned)C_)) { \
        const float* cp_ = klL + (size_t)c_ * pitchT; \
        BK##0 = cp_[0]; BK##1 = cp_[1]; BK##2 = cp_[2]; BK##3 = cp_[3]; \
        BK##4 = cp_[4]; BK##5 = cp_[5]; BK##6 = cp_[6]; \
    } \
}

// COMPUTE(S, bank): cell v = min(diag + ds, left + (W+ds), up + (W+ds)); chain = 2 dep ops/cell
#define COMPUTE(S, BK) { \
    int c_ = (S) - lane; \
    float last_ = 0.f; \
    if ((unsigned)c_ <= (unsigned)C_) { \
        float u_  = lane0 ? BIGV : recv_cur; \
        float dg_ = (c_ == 0) ? (lane0 ? 0.f : BIGV) : (lane0 ? BIGV : recv_prev); \
        float B0_ = WARP_ + BK##0, B1_ = WARP_ + BK##1, B2_ = WARP_ + BK##2, \
              B3_ = WARP_ + BK##3, B4_ = WARP_ + BK##4, B5_ = WARP_ + BK##5, \
              B6_ = WARP_ + BK##6; \
        float P0_ = fminf(dg_ + BK##0, p0 + B0_); \
        float P1_ = fminf(p0 + BK##1, p1 + B1_); \
        float P2_ = fminf(p1 + BK##2, p2 + B2_); \
        float P3_ = fminf(p2 + BK##3, p3 + B3_); \
        float P4_ = fminf(p3 + BK##4, p4 + B4_); \
        float P5_ = fminf(p4 + BK##5, p5 + B5_); \
        float P6_ = fminf(p5 + BK##6, p6 + B6_); \
        u_ = fminf(P0_, u_ + B0_); p0 = u_; \
        u_ = fminf(P1_, u_ + B1_); p1 = u_; \
        u_ = fminf(P2_, u_ + B2_); p2 = u_; \
        u_ = fminf(P3_, u_ + B3_); p3 = u_; \
        u_ = fminf(P4_, u_ + B4_); p4 = u_; \
        u_ = fminf(P5_, u_ + B5_); p5 = u_; \
        u_ = fminf(P6_, u_ + B6_); p6 = u_; \
        last_ = u_; \
    } \
    recv_prev = recv_cur; \
    recv_cur  = __shfl_up(last_, 1); \
}

// Fused: blocks 0..7 = barrier-free single-wave soft-DTW (mask-free, depth-4 prefetch);
//        blocks 8..  = grid-stride elementwise reductions (float4).
__global__ __launch_bounds__(512, 1) void main_kernel(
    const float* __restrict__ mel, const float* __restrict__ melh,
    const float* __restrict__ sg,  const float* __restrict__ se,
    const float* __restrict__ fr,  const float* __restrict__ ff,
    const float* __restrict__ dur, float* ws) {
    __shared__ float sbuf[64];
    int bid = blockIdx.x, tid = threadIdx.x;
    if (bid < 8) {
        if (tid >= 64) return;
        int lane = tid;
        bool lane0 = (lane == 0);
        int b = bid & 3, which = bid >> 2;
        int R_, C_, pitchT;
        const float* klT;
        if (which == 0) {
            R_ = TP_; C_ = TQ_; pitchT = KL1_PITCHT;
            klT = ws + KL1_OFF + (size_t)b * KL1_NCOL * KL1_PITCHT;
        } else {
            R_ = TQ_; C_ = TP_; pitchT = KL2_PITCHT;
            klT = ws + KL2_OFF + (size_t)b * KL2_NCOL * KL2_PITCHT;
        }
        // D has (R_+1) rows x (C_+1) cols, masks baked in. Lane owns D-rows r0..r0+6.
        const int RB = 7;
        int r0 = lane * RB;
        int lres = R_ / RB;                  // lane holding the answer row R_
        int kres = R_ - lres * RB;
        bool rvalid = (lane <= lres);
        const float* klL = klT + r0;
        float p0=BIGV,p1=BIGV,p2=BIGV,p3=BIGV,p4=BIGV,p5=BIGV,p6=BIGV;
        float bkA0=0,bkA1=0,bkA2=0,bkA3=0,bkA4=0,bkA5=0,bkA6=0;
        float bkB0=0,bkB1=0,bkB2=0,bkB3=0,bkB4=0,bkB5=0,bkB6=0;
        float bkC0=0,bkC1=0,bkC2=0,bkC3=0,bkC4=0,bkC5=0,bkC6=0;
        float bkD0=0,bkD1=0,bkD2=0,bkD3=0,bkD4=0,bkD5=0,bkD6=0;
        float recv_cur = BIGV, recv_prev = BIGV;
        int tmax = C_ + lres;                // lane lres computes col C_ at step tmax
        ISSUE(bkA, 0) ISSUE(bkB, 1) ISSUE(bkC, 2) ISSUE(bkD, 3)
        for (int t = 0; t <= tmax; t += 4) {
            COMPUTE(t,     bkA)  ISSUE(bkA, t + 4)
            COMPUTE(t + 1, bkB)  ISSUE(bkB, t + 5)
            COMPUTE(t + 2, bkC)  ISSUE(bkC, t + 6)
            COMPUTE(t + 3, bkD)  ISSUE(bkD, t + 7)
        }
        float q0 = __shfl(p0, lres), q1 = __shfl(p1, lres), q2 = __shfl(p2, lres),
              q3 = __shfl(p3, lres), q4 = __shfl(p4, lres), q5 = __shfl(p5, lres),
              q6 = __shfl(p6, lres);
        if (lane0) {
            float res = (kres == 0) ? q0 : (kres == 1) ? q1 : (kres == 2) ? q2 :
                        (kres == 3) ? q3 : (kres == 4) ? q4 : (kres == 5) ? q5 : q6;
            ws[DTW_OFF + which * 4 + b] = res;
        }
    } else {
        // ---------------- reductions ----------------
        int rid = bid - 8;
        long NR = (long)gridDim.x - 8;
        const float4* fr4   = (const float4*)fr;
        const float4* ff4   = (const float4*)ff;
        const float4* sg4   = (const float4*)sg;
        const float4* se4   = (const float4*)se;
        const float4* mel4  = (const float4*)mel;
        const float4* melh4 = (const float4*)melh;
        const float4* dur4  = (const float4*)dur;
        const long E0 = 12582912;       // feats (24*4*128*4096/4)
        const long E1 = E0 + 49152;     // gen   (6*4*8192/4)
        const long E2 = E1 + 49152;     // e2e
        const long E3 = E2 + 10240;     // mel   (4*80*128/4)
        const long E4 = E3 + 350;       // dur   (1400/4)
        float a0=0.f,a1=0.f,a2=0.f,a3=0.f,a4=0.f;
        long stride = NR * 512;
        for (long v = (long)rid * 512 + tid; v < E4; v += stride) {
            if (v < E0) {
                float4 x = fr4[v], y = ff4[v];
                a2 += fabsf(x.x - y.x) + fabsf(x.y - y.y) + fabsf(x.z - y.z) + fabsf(x.w - y.w);
            } else if (v < E1) {
                float4 s = sg4[v - E0]; float e;
                e = 1.f - s.x; a0 += e * e; e = 1.f - s.y; a0 += e * e;
                e = 1.f - s.z; a0 += e * e; e = 1.f - s.w; a0 += e * e;
            } else if (v < E2) {
                float4 s = se4[v - E1]; float e;
                e = 1.f - s.x; a1 += e * e; e = 1.f - s.y; a1 += e * e;
                e = 1.f - s.z; a1 += e * e; e = 1.f - s.w; a1 += e * e;
            } else if (v < E3) {
                float4 x = mel4[v - E2], y = melh4[v - E2];
                a3 += fabsf(x.x - y.x) + fabsf(x.y - y.y) + fabsf(x.z - y.z) + fabsf(x.w - y.w);
            } else {
                float4 x = dur4[v - E3]; a4 += x.x + x.y + x.z + x.w;
            }
        }
        float vals[5] = {a0, a1, a2, a3, a4};
#pragma unroll
        for (int q = 0; q < 5; ++q) {
            float v = vals[q];
            for (int off = 32; off > 0; off >>= 1) v += __shfl_xor(v, off);
            if ((tid & 63) == 0) sbuf[(tid >> 6) * 8 + q] = v;
        }
        __syncthreads();
        if (tid < 5) {
            float s = 0.f;
            for (int w = 0; w < 8; ++w) s += sbuf[w * 8 + tid];
            atomicAdd(&ws[ACC_OFF + tid], s);
        }
    }
}

// mask sums (tiny): acc[5] = sum(pmask), acc[6] = sum(zmask)
__global__ void masksum_kernel(const float* __restrict__ pmask,
                               const float* __restrict__ zmask,
                               float* __restrict__ ws) {
    int tid = threadIdx.x;   // 256 threads, 1 block
    float a5 = 0.f, a6 = 0.f;
    for (int v = tid; v < B_ * TP_; v += 256) a5 += pmask[v];
    for (int v = tid; v < B_ * TQ_; v += 256) a6 += zmask[v];
    __shared__ float s5[4], s6[4];
    for (int off = 32; off > 0; off >>= 1) { a5 += __shfl_xor(a5, off); a6 += __shfl_xor(a6, off); }
    if ((tid & 63) == 0) { s5[tid >> 6] = a5; s6[tid >> 6] = a6; }
    __syncthreads();
    if (tid == 0) {
        ws[5] = s5[0] + s5[1] + s5[2] + s5[3];
        ws[6] = s6[0] + s6[1] + s6[2] + s6[3];
    }
}

__global__ void final_kernel(const float* __restrict__ ws,
                             const float* __restrict__ ldl,
                             float* __restrict__ out) {
    if (threadIdx.x == 0 && blockIdx.x == 0) {
        float gen  = ws[0] * (1.f / 32768.f);
        float e2e  = ws[1] * (1.f / 32768.f);
        float fm   = ws[2] * (2.f / 2097152.f);
        float melv = ws[3] * (45.f / 40960.f);
        float durv = ws[4];
        float dlen = logf(ldl[0] + 1e-6f);
        float kl  = (ws[DTW_OFF + 0] + ws[DTW_OFF + 1] + ws[DTW_OFF + 2] + ws[DTW_OFF + 3]) / ws[5];
        float klf = (ws[DTW_OFF + 4] + ws[DTW_OFF + 5] + ws[DTW_OFF + 6] + ws[DTW_OFF + 7]) / ws[6];
        out[0] = gen + e2e + fm + melv + durv + dlen + kl + klf;
    }
}

extern "C" void kernel_launch(void* const* d_in, const int* in_sizes, int n_in,
                              void* d_out, int out_size, void* d_ws, size_t ws_size,
                              hipStream_t stream) {
    const float* mel    = (const float*)d_in[0];
    const float* melh   = (const float*)d_in[1];
    const float* sg     = (const float*)d_in[2];
    const float* se     = (const float*)d_in[3];
    const float* fr     = (const float*)d_in[4];
    const float* ff     = (const float*)d_in[5];
    const float* dur    = (const float*)d_in[6];
    const float* ldl    = (const float*)d_in[7];
    // d_in[8] = loss_pitch (unused by reference)
    const float* z_p    = (const float*)d_in[9];
    const float* m_p    = (const float*)d_in[10];
    const float* logs_p = (const float*)d_in[11];
    const float* z_q    = (const float*)d_in[12];
    const float* m_q    = (const float*)d_in[13];
    const float* logs_q = (const float*)d_in[14];
    const float* pmask  = (const float*)d_in[15];
    const float* zmask  = (const float*)d_in[16];  // (B,1,TQ) == flat (B,TQ)
    float* ws  = (float*)d_ws;
    float* out = (float*)d_out;

    sl_kernel<<<12, 256, 0, stream>>>(logs_p, logs_q, ws);
    masksum_kernel<<<1, 256, 0, stream>>>(pmask, zmask, ws);
    kl_kernel<<<dim3(13, 13, 8), dim3(16, 16), 0, stream>>>(
        m_p, logs_p, z_p, m_q, logs_q, z_q, pmask, zmask, ws);
    main_kernel<<<8 + 1016, 512, 0, stream>>>(mel, melh, sg, se, fr, ff, dur, ws);
    final_kernel<<<1, 64, 0, stream>>>(ws, ldl, out);
}

// Round 6
// 188.156 us; speedup vs baseline: 3.5733x; 2.0102x over previous
//
#include <hip/hip_runtime.h>
#include <math.h>

// ---------------- problem constants ----------------
#define GAMMA_ 0.01f
#define WARP_  134.4f
#define INFV   100000.0f
#define BIGV   1000000000.0f

#define B_  4
#define H_  192
#define TP_ 350
#define TQ_ 400

// ---------------- workspace layout (float offsets) ----------------
// acc[0]=gen acc[1]=e2e acc[2]=fm acc[3]=mel acc[4]=dur acc[5]=sum_pm acc[6]=sum_qm
#define ACC_OFF 0
#define DTW_OFF 16                          // 8 results: [which*4 + b]
#define SLP_OFF 32                          // sum_h logs_p  [B][350]
#define SLQ_OFF (SLP_OFF + B_*TP_)          // sum_h logs_q  [B][400]
// D-matrices with masks BAKED IN (incl. pad row/col), transposed [J][I]:
// klT1 [B][401 cols][pitch 352]  (I = 0..350)
#define KL1_OFF 3072
#define KL1_NCOL 401
#define KL1_PITCHT 352                      // mult of 4; >= 351 + 1
// klT2 [B][351 cols][pitch 408]  (I = 0..400; pitch >= 400+8 so lane base 400 reads in-col)
#define KL2_OFF (KL1_OFF + B_*KL1_NCOL*KL1_PITCHT)
#define KL2_NCOL 351
#define KL2_PITCHT 408
// end = 3072 + 564608 + 572832 = 1,140,512 floats ≈ 4.56 MB. All DTW loads stay
// strictly inside their own column (rowoff clamped to pitch-8) -> no OOB ever.

typedef float f4_t __attribute__((ext_vector_type(4)));

// per-position sums over h of logs_p / logs_q  (+ zero the accumulators)
__global__ void sl_kernel(const float* __restrict__ logs_p,
                          const float* __restrict__ logs_q,
                          float* __restrict__ ws) {
    int t = blockIdx.x * 256 + threadIdx.x;
    if (t < 32) ws[ACC_OFF + t] = 0.f;
    if (t < B_ * TP_) {
        int b = t / TP_, i = t % TP_;
        const float* p = logs_p + (size_t)b * H_ * TP_ + i;
        float s = 0.f;
        for (int h = 0; h < H_; ++h) s += p[(size_t)h * TP_];
        ws[SLP_OFF + t] = s;
    } else if (t < B_ * TP_ + B_ * TQ_) {
        int t2 = t - B_ * TP_;
        int b = t2 / TQ_, j = t2 % TQ_;
        const float* p = logs_q + (size_t)b * H_ * TQ_ + j;
        float s = 0.f;
        for (int h = 0; h < H_; ++h) s += p[(size_t)h * TQ_];
        ws[SLQ_OFF + t2] = s;
    }
}

// Writes the fully-masked D matrix (transposed, [J][I]) including pad row I=R and
// pad col J=C:  D = (pb&&qb) ? kl : (pb^qb ? INF : 0),  pb/qb false on pads.
__global__ void kl_kernel(const float* __restrict__ mp, const float* __restrict__ lsp,
                          const float* __restrict__ zp,
                          const float* __restrict__ mq, const float* __restrict__ lsq,
                          const float* __restrict__ zq,
                          const float* __restrict__ pmask, const float* __restrict__ zmask,
                          float* __restrict__ ws) {
    int which = blockIdx.z >> 2;
    int b     = blockIdx.z & 3;
    const float *mS, *lS, *zS, *SLrow, *SLcol, *rm, *cm; float* out; int R, C, pitchT;
    if (which == 0) { mS=mp; lS=lsp; zS=zp; SLrow=ws+SLP_OFF; SLcol=ws+SLQ_OFF;
                      rm=pmask + b*TP_; cm=zmask + b*TQ_;
                      out=ws+KL1_OFF + (size_t)b*KL1_NCOL*KL1_PITCHT;
                      R=TP_; C=TQ_; pitchT=KL1_PITCHT; }
    else            { mS=mq; lS=lsq; zS=zq; SLrow=ws+SLQ_OFF; SLcol=ws+SLP_OFF;
                      rm=zmask + b*TQ_; cm=pmask + b*TP_;
                      out=ws+KL2_OFF + (size_t)b*KL2_NCOL*KL2_PITCHT;
                      R=TQ_; C=TP_; pitchT=KL2_PITCHT; }
    int i0 = blockIdx.x * 32;       // I (m-side, minor dim of klT), range [0, R]
    int j0 = blockIdx.y * 32;       // J (z-side, major dim of klT), range [0, C]
    if (i0 > R || j0 > C) return;
    __shared__ __align__(16) float wS [16][32];
    __shared__ __align__(16) float mSh[16][32];
    __shared__ __align__(16) float zSh[16][32];
    const float* mB = mS + (size_t)b * H_ * R;
    const float* lB = lS + (size_t)b * H_ * R;
    const float* zB = zS + (size_t)b * H_ * C;
    int tx = threadIdx.x, ty = threadIdx.y;    // tx -> i, ty -> j
    int t  = ty * 16 + tx;
    float a00 = 0.f, a01 = 0.f, a10 = 0.f, a11 = 0.f;  // a[jj][ii]
    for (int h0 = 0; h0 < H_; h0 += 16) {
        for (int e = t; e < 512; e += 256) {
            int hh = e >> 5, cc = e & 31;
            int h = h0 + hh;
            int gi = i0 + cc, gj = j0 + cc;
            float wv = 0.f, mv = 0.f;
            if (gi < R) {
                wv = __expf(-2.f * lB[(size_t)h * R + gi]);
                mv = mB[(size_t)h * R + gi];
            }
            wS[hh][cc] = wv; mSh[hh][cc] = mv;
            zSh[hh][cc] = (gj < C) ? zB[(size_t)h * C + gj] : 0.f;
        }
        __syncthreads();
#pragma unroll
        for (int kk = 0; kk < 16; ++kk) {
            float2 wv = *(const float2*)&wS [kk][tx * 2];
            float2 mv = *(const float2*)&mSh[kk][tx * 2];
            float2 zv = *(const float2*)&zSh[kk][ty * 2];
            float d;
            d = zv.x - mv.x; a00 += wv.x * d * d;
            d = zv.x - mv.y; a01 += wv.y * d * d;
            d = zv.y - mv.x; a10 += wv.x * d * d;
            d = zv.y - mv.y; a11 += wv.y * d * d;
        }
        __syncthreads();
    }
    float accs[2][2] = {{a00, a01}, {a10, a11}};
    for (int jj = 0; jj < 2; ++jj)
        for (int ii = 0; ii < 2; ++ii) {
            int I = i0 + tx * 2 + ii, J = j0 + ty * 2 + jj;
            if (I <= R && J <= C) {
                bool pbI = (I < R) && (rm[I] != 0.f);
                bool qbJ = (J < C) && (cm[J] != 0.f);
                float v;
                if (pbI & qbJ)
                    v = SLrow[b * R + I] - SLcol[b * C + J] - 0.5f * H_ + 0.5f * accs[jj][ii];
                else
                    v = (pbI ^ qbJ) ? INFV : 0.f;
                out[(size_t)J * pitchT + I] = v;
            }
        }
}

// ---------------- DTW macros ----------------
// ISSUE: 2x aligned float4 loads (8 rows). Column clamped to [0, C_]; row base
// pre-clamped to pitch-8 => always in-bounds, always 16B-aligned.
#define ISSUE(BK, S) { \
    int c_ = (S) - lane; \
    c_ = c_ < 0 ? 0 : (c_ > C_ ? C_ : c_); \
    const f4_t* cp_ = (const f4_t*)(klL + (size_t)c_ * pitchT); \
    BK##a = cp_[0]; BK##b = cp_[1]; \
}

#define SB() __builtin_amdgcn_sched_barrier(0)

// COMPUTE: v = d + min(diag, up+W, left+W), reassociated to 2 dependent ops/cell.
#define COMPUTE(S, BK) { \
    int c_ = (S) - lane; \
    float last_ = 0.f; \
    if ((unsigned)c_ <= (unsigned)C_) { \
        float u_  = lane0 ? BIGV : recv_cur; \
        float dg_ = (c_ == 0) ? (lane0 ? 0.f : BIGV) : (lane0 ? BIGV : recv_prev); \
        float d0_ = BK##a.x, d1_ = BK##a.y, d2_ = BK##a.z, d3_ = BK##a.w; \
        float d4_ = BK##b.x, d5_ = BK##b.y, d6_ = BK##b.z, d7_ = BK##b.w; \
        float B0_ = WARP_ + d0_, B1_ = WARP_ + d1_, B2_ = WARP_ + d2_, \
              B3_ = WARP_ + d3_, B4_ = WARP_ + d4_, B5_ = WARP_ + d5_, \
              B6_ = WARP_ + d6_, B7_ = WARP_ + d7_; \
        float P0_ = fminf(dg_ + d0_, p0 + B0_); \
        float P1_ = fminf(p0 + d1_, p1 + B1_); \
        float P2_ = fminf(p1 + d2_, p2 + B2_); \
        float P3_ = fminf(p2 + d3_, p3 + B3_); \
        float P4_ = fminf(p3 + d4_, p4 + B4_); \
        float P5_ = fminf(p4 + d5_, p5 + B5_); \
        float P6_ = fminf(p5 + d6_, p6 + B6_); \
        float P7_ = fminf(p6 + d7_, p7 + B7_); \
        u_ = fminf(P0_, u_ + B0_); p0 = u_; \
        u_ = fminf(P1_, u_ + B1_); p1 = u_; \
        u_ = fminf(P2_, u_ + B2_); p2 = u_; \
        u_ = fminf(P3_, u_ + B3_); p3 = u_; \
        u_ = fminf(P4_, u_ + B4_); p4 = u_; \
        u_ = fminf(P5_, u_ + B5_); p5 = u_; \
        u_ = fminf(P6_, u_ + B6_); p6 = u_; \
        u_ = fminf(P7_, u_ + B7_); p7 = u_; \
        last_ = u_; \
    } \
    recv_prev = recv_cur; \
    recv_cur  = __shfl_up(last_, 1); \
}

// Fused: blocks 0..7 = barrier-free single-wave soft-DTW (depth-4 pinned pipeline);
//        blocks 8..  = grid-stride elementwise reductions (float4).
__global__ __launch_bounds__(512, 1) void main_kernel(
    const float* __restrict__ mel, const float* __restrict__ melh,
    const float* __restrict__ sg,  const float* __restrict__ se,
    const float* __restrict__ fr,  const float* __restrict__ ff,
    const float* __restrict__ dur, float* ws) {
    __shared__ float sbuf[64];
    int bid = blockIdx.x, tid = threadIdx.x;
    if (bid < 8) {
        if (tid >= 64) return;
        int lane = tid;
        bool lane0 = (lane == 0);
        int b = bid & 3, which = bid >> 2;
        int R_, C_, pitchT;
        const float* klT;
        if (which == 0) {
            R_ = TP_; C_ = TQ_; pitchT = KL1_PITCHT;
            klT = ws + KL1_OFF + (size_t)b * KL1_NCOL * KL1_PITCHT;
        } else {
            R_ = TQ_; C_ = TP_; pitchT = KL2_PITCHT;
            klT = ws + KL2_OFF + (size_t)b * KL2_NCOL * KL2_PITCHT;
        }
        // D has (R_+1) rows x (C_+1) cols, masks baked in. Lane owns D-rows r0..r0+7.
        const int RB = 8;
        int r0 = lane * RB;
        int lres = R_ / RB;                  // lane holding the answer row R_
        int kres = R_ - lres * RB;           // kl1: lane 43 / k 6; kl2: lane 50 / k 0
        int rowoff = r0 < (pitchT - 8) ? r0 : (pitchT - 8);   // clamp keeps loads in-column
        const float* klL = klT + rowoff;
        float p0=BIGV,p1=BIGV,p2=BIGV,p3=BIGV,p4=BIGV,p5=BIGV,p6=BIGV,p7=BIGV;
        f4_t bkAa, bkAb, bkBa, bkBb, bkCa, bkCb, bkDa, bkDb;
        float recv_cur = BIGV, recv_prev = BIGV;
        int tmax = C_ + lres;                // lane lres computes col C_ at step tmax
        ISSUE(bkA, 0) ISSUE(bkB, 1) ISSUE(bkC, 2) ISSUE(bkD, 3)
        SB();
        for (int t = 0; t <= tmax; t += 4) {
            COMPUTE(t,     bkA)  SB();  ISSUE(bkA, t + 4)  SB();
            COMPUTE(t + 1, bkB)  SB();  ISSUE(bkB, t + 5)  SB();
            COMPUTE(t + 2, bkC)  SB();  ISSUE(bkC, t + 6)  SB();
            COMPUTE(t + 3, bkD)  SB();  ISSUE(bkD, t + 7)  SB();
        }
        float q0 = __shfl(p0, lres), q1 = __shfl(p1, lres), q2 = __shfl(p2, lres),
              q3 = __shfl(p3, lres), q4 = __shfl(p4, lres), q5 = __shfl(p5, lres),
              q6 = __shfl(p6, lres), q7 = __shfl(p7, lres);
        if (lane0) {
            float res = (kres == 0) ? q0 : (kres == 1) ? q1 : (kres == 2) ? q2 :
                        (kres == 3) ? q3 : (kres == 4) ? q4 : (kres == 5) ? q5 :
                        (kres == 6) ? q6 : q7;
            ws[DTW_OFF + which * 4 + b] = res;
        }
    } else {
        // ---------------- reductions ----------------
        int rid = bid - 8;
        long NR = (long)gridDim.x - 8;
        const float4* fr4   = (const float4*)fr;
        const float4* ff4   = (const float4*)ff;
        const float4* sg4   = (const float4*)sg;
        const float4* se4   = (const float4*)se;
        const float4* mel4  = (const float4*)mel;
        const float4* melh4 = (const float4*)melh;
        const float4* dur4  = (const float4*)dur;
        const long E0 = 12582912;       // feats (24*4*128*4096/4)
        const long E1 = E0 + 49152;     // gen   (6*4*8192/4)
        const long E2 = E1 + 49152;     // e2e
        const long E3 = E2 + 10240;     // mel   (4*80*128/4)
        const long E4 = E3 + 350;       // dur   (1400/4)
        float a0=0.f,a1=0.f,a2=0.f,a3=0.f,a4=0.f;
        long stride = NR * 512;
        for (long v = (long)rid * 512 + tid; v < E4; v += stride) {
            if (v < E0) {
                float4 x = fr4[v], y = ff4[v];
                a2 += fabsf(x.x - y.x) + fabsf(x.y - y.y) + fabsf(x.z - y.z) + fabsf(x.w - y.w);
            } else if (v < E1) {
                float4 s = sg4[v - E0]; float e;
                e = 1.f - s.x; a0 += e * e; e = 1.f - s.y; a0 += e * e;
                e = 1.f - s.z; a0 += e * e; e = 1.f - s.w; a0 += e * e;
            } else if (v < E2) {
                float4 s = se4[v - E1]; float e;
                e = 1.f - s.x; a1 += e * e; e = 1.f - s.y; a1 += e * e;
                e = 1.f - s.z; a1 += e * e; e = 1.f - s.w; a1 += e * e;
            } else if (v < E3) {
                float4 x = mel4[v - E2], y = melh4[v - E2];
                a3 += fabsf(x.x - y.x) + fabsf(x.y - y.y) + fabsf(x.z - y.z) + fabsf(x.w - y.w);
            } else {
                float4 x = dur4[v - E3]; a4 += x.x + x.y + x.z + x.w;
            }
        }
        float vals[5] = {a0, a1, a2, a3, a4};
#pragma unroll
        for (int q = 0; q < 5; ++q) {
            float v = vals[q];
            for (int off = 32; off > 0; off >>= 1) v += __shfl_xor(v, off);
            if ((tid & 63) == 0) sbuf[(tid >> 6) * 8 + q] = v;
        }
        __syncthreads();
        if (tid < 5) {
            float s = 0.f;
            for (int w = 0; w < 8; ++w) s += sbuf[w * 8 + tid];
            atomicAdd(&ws[ACC_OFF + tid], s);
        }
    }
}

// mask sums (tiny): acc[5] = sum(pmask), acc[6] = sum(zmask)
__global__ void masksum_kernel(const float* __restrict__ pmask,
                               const float* __restrict__ zmask,
                               float* __restrict__ ws) {
    int tid = threadIdx.x;   // 256 threads, 1 block
    float a5 = 0.f, a6 = 0.f;
    for (int v = tid; v < B_ * TP_; v += 256) a5 += pmask[v];
    for (int v = tid; v < B_ * TQ_; v += 256) a6 += zmask[v];
    __shared__ float s5[4], s6[4];
    for (int off = 32; off > 0; off >>= 1) { a5 += __shfl_xor(a5, off); a6 += __shfl_xor(a6, off); }
    if ((tid & 63) == 0) { s5[tid >> 6] = a5; s6[tid >> 6] = a6; }
    __syncthreads();
    if (tid == 0) {
        ws[5] = s5[0] + s5[1] + s5[2] + s5[3];
        ws[6] = s6[0] + s6[1] + s6[2] + s6[3];
    }
}

__global__ void final_kernel(const float* __restrict__ ws,
                             const float* __restrict__ ldl,
                             float* __restrict__ out) {
    if (threadIdx.x == 0 && blockIdx.x == 0) {
        float gen  = ws[0] * (1.f / 32768.f);
        float e2e  = ws[1] * (1.f / 32768.f);
        float fm   = ws[2] * (2.f / 2097152.f);
        float melv = ws[3] * (45.f / 40960.f);
        float durv = ws[4];
        float dlen = logf(ldl[0] + 1e-6f);
        float kl  = (ws[DTW_OFF + 0] + ws[DTW_OFF + 1] + ws[DTW_OFF + 2] + ws[DTW_OFF + 3]) / ws[5];
        float klf = (ws[DTW_OFF + 4] + ws[DTW_OFF + 5] + ws[DTW_OFF + 6] + ws[DTW_OFF + 7]) / ws[6];
        out[0] = gen + e2e + fm + melv + durv + dlen + kl + klf;
    }
}

extern "C" void kernel_launch(void* const* d_in, const int* in_sizes, int n_in,
                              void* d_out, int out_size, void* d_ws, size_t ws_size,
                              hipStream_t stream) {
    const float* mel    = (const float*)d_in[0];
    const float* melh   = (const float*)d_in[1];
    const float* sg     = (const float*)d_in[2];
    const float* se     = (const float*)d_in[3];
    const float* fr     = (const float*)d_in[4];
    const float* ff     = (const float*)d_in[5];
    const float* dur    = (const float*)d_in[6];
    const float* ldl    = (const float*)d_in[7];
    // d_in[8] = loss_pitch (unused by reference)
    const float* z_p    = (const float*)d_in[9];
    const float* m_p    = (const float*)d_in[10];
    const float* logs_p = (const float*)d_in[11];
    const float* z_q    = (const float*)d_in[12];
    const float* m_q    = (const float*)d_in[13];
    const float* logs_q = (const float*)d_in[14];
    const float* pmask  = (const float*)d_in[15];
    const float* zmask  = (const float*)d_in[16];  // (B,1,TQ) == flat (B,TQ)
    float* ws  = (float*)d_ws;
    float* out = (float*)d_out;

    sl_kernel<<<12, 256, 0, stream>>>(logs_p, logs_q, ws);
    masksum_kernel<<<1, 256, 0, stream>>>(pmask, zmask, ws);
    kl_kernel<<<dim3(13, 13, 8), dim3(16, 16), 0, stream>>>(
        m_p, logs_p, z_p, m_q, logs_q, z_q, pmask, zmask, ws);
    main_kernel<<<8 + 1016, 512, 0, stream>>>(mel, melh, sg, se, fr, ff, dur, ws);
    final_kernel<<<1, 64, 0, stream>>>(ws, ldl, out);
}

// Round 7
// 166.881 us; speedup vs baseline: 4.0289x; 1.1275x over previous
//
#include <hip/hip_runtime.h>
#include <math.h>

// ---------------- problem constants ----------------
#define GAMMA_ 0.01f
#define WARP_  134.4f
#define INFV   100000.0f
#define BIGV   1000000000.0f

#define B_  4
#define H_  192
#define TP_ 350
#define TQ_ 400

// ---------------- workspace layout (float offsets) ----------------
// acc[0]=gen acc[1]=e2e acc[2]=fm acc[3]=mel acc[4]=dur acc[5]=sum_pm acc[6]=sum_qm
#define ACC_OFF 0
#define DTW_OFF 16                          // 8 results: [which*4 + b]
#define SLP_OFF 32                          // sum_h logs_p  [B][350]
#define SLQ_OFF (SLP_OFF + B_*TP_)          // sum_h logs_q  [B][400]
// D-matrices with masks BAKED IN (incl. pad row/col), transposed [J][I]:
#define KL1_OFF 3072
#define KL1_NCOL 401
#define KL1_PITCHT 352
#define KL2_OFF (KL1_OFF + B_*KL1_NCOL*KL1_PITCHT)
#define KL2_NCOL 351
#define KL2_PITCHT 408

// LDS ring: 67 column slots x 416 bf16 (832 B each). 67 >= 66 = 15(chunk skew)+51(lane span).
#define RING_SLOTS 67
#define RING_PITCH 416                      // bf16 elems; 832 B, mult of 16

typedef float f4_t __attribute__((ext_vector_type(4)));

__device__ __forceinline__ unsigned pk2(float a, float b) {
    unsigned ua = __float_as_uint(a), ub = __float_as_uint(b);
    ua = (ua + 0x7FFFu + ((ua >> 16) & 1u)) >> 16;          // RTN bf16 of a (low half)
    ub = (ub + 0x7FFFu + ((ub >> 16) & 1u)) & 0xFFFF0000u;  // RTN bf16 of b (high half)
    return ua | ub;
}

// per-position sums over h of logs_p / logs_q  (+ zero the accumulators)
__global__ void sl_kernel(const float* __restrict__ logs_p,
                          const float* __restrict__ logs_q,
                          float* __restrict__ ws) {
    int t = blockIdx.x * 256 + threadIdx.x;
    if (t < 32) ws[ACC_OFF + t] = 0.f;
    if (t < B_ * TP_) {
        int b = t / TP_, i = t % TP_;
        const float* p = logs_p + (size_t)b * H_ * TP_ + i;
        float s = 0.f;
        for (int h = 0; h < H_; ++h) s += p[(size_t)h * TP_];
        ws[SLP_OFF + t] = s;
    } else if (t < B_ * TP_ + B_ * TQ_) {
        int t2 = t - B_ * TP_;
        int b = t2 / TQ_, j = t2 % TQ_;
        const float* p = logs_q + (size_t)b * H_ * TQ_ + j;
        float s = 0.f;
        for (int h = 0; h < H_; ++h) s += p[(size_t)h * TQ_];
        ws[SLQ_OFF + t2] = s;
    }
}

// Writes the fully-masked D matrix (transposed, [J][I]) including pad row I=R and
// pad col J=C:  D = (pb&&qb) ? kl : (pb^qb ? INF : 0),  pb/qb false on pads.
__global__ void kl_kernel(const float* __restrict__ mp, const float* __restrict__ lsp,
                          const float* __restrict__ zp,
                          const float* __restrict__ mq, const float* __restrict__ lsq,
                          const float* __restrict__ zq,
                          const float* __restrict__ pmask, const float* __restrict__ zmask,
                          float* __restrict__ ws) {
    int which = blockIdx.z >> 2;
    int b     = blockIdx.z & 3;
    const float *mS, *lS, *zS, *SLrow, *SLcol, *rm, *cm; float* out; int R, C, pitchT;
    if (which == 0) { mS=mp; lS=lsp; zS=zp; SLrow=ws+SLP_OFF; SLcol=ws+SLQ_OFF;
                      rm=pmask + b*TP_; cm=zmask + b*TQ_;
                      out=ws+KL1_OFF + (size_t)b*KL1_NCOL*KL1_PITCHT;
                      R=TP_; C=TQ_; pitchT=KL1_PITCHT; }
    else            { mS=mq; lS=lsq; zS=zq; SLrow=ws+SLQ_OFF; SLcol=ws+SLP_OFF;
                      rm=zmask + b*TQ_; cm=pmask + b*TP_;
                      out=ws+KL2_OFF + (size_t)b*KL2_NCOL*KL2_PITCHT;
                      R=TQ_; C=TP_; pitchT=KL2_PITCHT; }
    int i0 = blockIdx.x * 32;
    int j0 = blockIdx.y * 32;
    if (i0 > R || j0 > C) return;
    __shared__ __align__(16) float wS [16][32];
    __shared__ __align__(16) float mSh[16][32];
    __shared__ __align__(16) float zSh[16][32];
    const float* mB = mS + (size_t)b * H_ * R;
    const float* lB = lS + (size_t)b * H_ * R;
    const float* zB = zS + (size_t)b * H_ * C;
    int tx = threadIdx.x, ty = threadIdx.y;
    int t  = ty * 16 + tx;
    float a00 = 0.f, a01 = 0.f, a10 = 0.f, a11 = 0.f;
    for (int h0 = 0; h0 < H_; h0 += 16) {
        for (int e = t; e < 512; e += 256) {
            int hh = e >> 5, cc = e & 31;
            int h = h0 + hh;
            int gi = i0 + cc, gj = j0 + cc;
            float wv = 0.f, mv = 0.f;
            if (gi < R) {
                wv = __expf(-2.f * lB[(size_t)h * R + gi]);
                mv = mB[(size_t)h * R + gi];
            }
            wS[hh][cc] = wv; mSh[hh][cc] = mv;
            zSh[hh][cc] = (gj < C) ? zB[(size_t)h * C + gj] : 0.f;
        }
        __syncthreads();
#pragma unroll
        for (int kk = 0; kk < 16; ++kk) {
            float2 wv = *(const float2*)&wS [kk][tx * 2];
            float2 mv = *(const float2*)&mSh[kk][tx * 2];
            float2 zv = *(const float2*)&zSh[kk][ty * 2];
            float d;
            d = zv.x - mv.x; a00 += wv.x * d * d;
            d = zv.x - mv.y; a01 += wv.y * d * d;
            d = zv.y - mv.x; a10 += wv.x * d * d;
            d = zv.y - mv.y; a11 += wv.y * d * d;
        }
        __syncthreads();
    }
    float accs[2][2] = {{a00, a01}, {a10, a11}};
    for (int jj = 0; jj < 2; ++jj)
        for (int ii = 0; ii < 2; ++ii) {
            int I = i0 + tx * 2 + ii, J = j0 + ty * 2 + jj;
            if (I <= R && J <= C) {
                bool pbI = (I < R) && (rm[I] != 0.f);
                bool qbJ = (J < C) && (cm[J] != 0.f);
                float v;
                if (pbI & qbJ)
                    v = SLrow[b * R + I] - SLcol[b * C + J] - 0.5f * H_ + 0.5f * accs[jj][ii];
                else
                    v = (pbI ^ qbJ) ? INFV : 0.f;
                out[(size_t)J * pitchT + I] = v;
            }
        }
}

// stager macros: load chunk q (8 cols) element (cc,ii) from klT; store to ring (bf16)
#define SLD(q, r, cc, ii, vv) { int col_ = ((q) << 3) + (cc); \
    if ((vv) && col_ <= C_) r = *(const f4_t*)(klT + (size_t)col_ * pitchT + ((ii) << 2)); }
#define SST(q, r, cc, ii, vv) { int col_ = ((q) << 3) + (cc); \
    if ((vv) && col_ <= C_) { int s_ = col_ - (col_ / RING_SLOTS) * RING_SLOTS; \
        uint2 u_; u_.x = pk2(r.x, r.y); u_.y = pk2(r.z, r.w); \
        *(uint2*)&ring[s_][(ii) << 2] = u_; } }

// Fused: blocks 0..7 = soft-DTW with producer-wave LDS ring (wave0 consumer, waves 1-7 stage);
//        blocks 8..  = grid-stride elementwise reductions (float4).
__global__ __launch_bounds__(512, 1) void main_kernel(
    const float* __restrict__ mel, const float* __restrict__ melh,
    const float* __restrict__ sg,  const float* __restrict__ se,
    const float* __restrict__ fr,  const float* __restrict__ ff,
    const float* __restrict__ dur, float* ws) {
    __shared__ __align__(16) unsigned short ring[RING_SLOTS + 2][RING_PITCH]; // +2 pad: dead-lane b128 overrun
    __shared__ float sbuf[64];
    int bid = blockIdx.x, tid = threadIdx.x;
    if (bid < 8) {
        int b = bid & 3, which = bid >> 2;
        int R_, C_, pitchT;
        const float* klT;
        if (which == 0) {
            R_ = TP_; C_ = TQ_; pitchT = KL1_PITCHT;
            klT = ws + KL1_OFF + (size_t)b * KL1_NCOL * KL1_PITCHT;
        } else {
            R_ = TQ_; C_ = TP_; pitchT = KL2_PITCHT;
            klT = ws + KL2_OFF + (size_t)b * KL2_NCOL * KL2_PITCHT;
        }
        int lres = R_ >> 3;                   // 43 (kl1) / 50 (kl2)
        int kres = R_ & 7;                    // 6 / 0
        int tmax = C_ + lres;
        int P = (tmax + 8) >> 3;              // 56 / 51 phases of 8 steps

        if (tid < 64) {
            // ---------------- consumer wave ----------------
            int lane = tid; bool lane0 = (lane == 0);
            float p0=BIGV,p1=BIGV,p2=BIGV,p3=BIGV,p4=BIGV,p5=BIGV,p6=BIGV,p7=BIGV;
            float recv_cur = BIGV, recv_prev = BIGV;
            __syncthreads();                  // B0: chunk 0 staged
            for (int p = 0; p < P; ++p) {
                int t0 = p << 3;
                int c0 = t0 - lane;
                int cr = c0 < 0 ? 0 : (c0 > C_ ? C_ : c0);
                int s0 = cr - (cr / RING_SLOTS) * RING_SLOTS;
                int4 rd = *(const int4*)&ring[s0][lane << 3];
#pragma unroll
                for (int i = 0; i < 8; ++i) {
                    int c = t0 + i - lane;
                    int4 ru = rd;
                    if (i < 7) {              // prefetch next column (stays within chunk <= p)
                        int cn = c + 1; cn = cn < 0 ? 0 : (cn > C_ ? C_ : cn);
                        int sn = cn - (cn / RING_SLOTS) * RING_SLOTS;
                        rd = *(const int4*)&ring[sn][lane << 3];
                    }
                    float last_ = 0.f;
                    if ((unsigned)c <= (unsigned)C_) {
                        float u_  = lane0 ? BIGV : recv_cur;
                        float dg_ = (c == 0) ? (lane0 ? 0.f : BIGV) : (lane0 ? BIGV : recv_prev);
                        float d0 = __uint_as_float((unsigned)ru.x << 16);
                        float d1 = __uint_as_float((unsigned)ru.x & 0xFFFF0000u);
                        float d2 = __uint_as_float((unsigned)ru.y << 16);
                        float d3 = __uint_as_float((unsigned)ru.y & 0xFFFF0000u);
                        float d4 = __uint_as_float((unsigned)ru.z << 16);
                        float d5 = __uint_as_float((unsigned)ru.z & 0xFFFF0000u);
                        float d6 = __uint_as_float((unsigned)ru.w << 16);
                        float d7 = __uint_as_float((unsigned)ru.w & 0xFFFF0000u);
                        float B0 = WARP_ + d0, B1 = WARP_ + d1, B2 = WARP_ + d2, B3 = WARP_ + d3;
                        float B4 = WARP_ + d4, B5 = WARP_ + d5, B6 = WARP_ + d6, B7 = WARP_ + d7;
                        float P0 = fminf(dg_ + d0, p0 + B0);
                        float P1 = fminf(p0 + d1, p1 + B1);
                        float P2 = fminf(p1 + d2, p2 + B2);
                        float P3 = fminf(p2 + d3, p3 + B3);
                        float P4 = fminf(p3 + d4, p4 + B4);
                        float P5 = fminf(p4 + d5, p5 + B5);
                        float P6 = fminf(p5 + d6, p6 + B6);
                        float P7 = fminf(p6 + d7, p7 + B7);
                        u_ = fminf(P0, u_ + B0); p0 = u_;
                        u_ = fminf(P1, u_ + B1); p1 = u_;
                        u_ = fminf(P2, u_ + B2); p2 = u_;
                        u_ = fminf(P3, u_ + B3); p3 = u_;
                        u_ = fminf(P4, u_ + B4); p4 = u_;
                        u_ = fminf(P5, u_ + B5); p5 = u_;
                        u_ = fminf(P6, u_ + B6); p6 = u_;
                        u_ = fminf(P7, u_ + B7); p7 = u_;
                        last_ = u_;
                    }
                    recv_prev = recv_cur;
                    recv_cur  = __shfl_up(last_, 1);
                }
                __syncthreads();              // barrier p+1: chunk p+1 writes complete
            }
            float q0 = __shfl(p0, lres), q1 = __shfl(p1, lres), q2 = __shfl(p2, lres),
                  q3 = __shfl(p3, lres), q4 = __shfl(p4, lres), q5 = __shfl(p5, lres),
                  q6 = __shfl(p6, lres), q7 = __shfl(p7, lres);
            if (lane0) {
                float res = (kres == 0) ? q0 : (kres == 1) ? q1 : (kres == 2) ? q2 :
                            (kres == 3) ? q3 : (kres == 4) ? q4 : (kres == 5) ? q5 :
                            (kres == 6) ? q6 : q7;
                ws[DTW_OFF + which * 4 + b] = res;
            }
        } else {
            // ---------------- stager waves (1..7) ----------------
            int st  = tid - 64;               // 0..447
            int n4  = pitchT >> 2;            // 88 / 102 float4s per column
            int tot = n4 << 3;                // per-chunk elements
            int cA = st / n4,  iA = st - cA * n4;
            int eB = st + 448; int cB = eB / n4, iB = eB - cB * n4;
            bool vA = st < tot, vB = eB < tot;
            f4_t rA = {0.f,0.f,0.f,0.f}, rB = {0.f,0.f,0.f,0.f};
            SLD(0, rA, cA, iA, vA) SLD(0, rB, cB, iB, vB)
            SST(0, rA, cA, iA, vA) SST(0, rB, cB, iB, vB)
            SLD(1, rA, cA, iA, vA) SLD(1, rB, cB, iB, vB)
            __syncthreads();                  // B0
            for (int p = 0; p < P; ++p) {
                SST(p + 1, rA, cA, iA, vA) SST(p + 1, rB, cB, iB, vB)
                SLD(p + 2, rA, cA, iA, vA) SLD(p + 2, rB, cB, iB, vB)
                __syncthreads();
            }
        }
    } else {
        // ---------------- reductions ----------------
        int rid = bid - 8;
        long NR = (long)gridDim.x - 8;
        const float4* fr4   = (const float4*)fr;
        const float4* ff4   = (const float4*)ff;
        const float4* sg4   = (const float4*)sg;
        const float4* se4   = (const float4*)se;
        const float4* mel4  = (const float4*)mel;
        const float4* melh4 = (const float4*)melh;
        const float4* dur4  = (const float4*)dur;
        const long E0 = 12582912;       // feats (24*4*128*4096/4)
        const long E1 = E0 + 49152;     // gen   (6*4*8192/4)
        const long E2 = E1 + 49152;     // e2e
        const long E3 = E2 + 10240;     // mel   (4*80*128/4)
        const long E4 = E3 + 350;       // dur   (1400/4)
        float a0=0.f,a1=0.f,a2=0.f,a3=0.f,a4=0.f;
        long stride = NR * 512;
        for (long v = (long)rid * 512 + tid; v < E4; v += stride) {
            if (v < E0) {
                float4 x = fr4[v], y = ff4[v];
                a2 += fabsf(x.x - y.x) + fabsf(x.y - y.y) + fabsf(x.z - y.z) + fabsf(x.w - y.w);
            } else if (v < E1) {
                float4 s = sg4[v - E0]; float e;
                e = 1.f - s.x; a0 += e * e; e = 1.f - s.y; a0 += e * e;
                e = 1.f - s.z; a0 += e * e; e = 1.f - s.w; a0 += e * e;
            } else if (v < E2) {
                float4 s = se4[v - E1]; float e;
                e = 1.f - s.x; a1 += e * e; e = 1.f - s.y; a1 += e * e;
                e = 1.f - s.z; a1 += e * e; e = 1.f - s.w; a1 += e * e;
            } else if (v < E3) {
                float4 x = mel4[v - E2], y = melh4[v - E2];
                a3 += fabsf(x.x - y.x) + fabsf(x.y - y.y) + fabsf(x.z - y.z) + fabsf(x.w - y.w);
            } else {
                float4 x = dur4[v - E3]; a4 += x.x + x.y + x.z + x.w;
            }
        }
        float vals[5] = {a0, a1, a2, a3, a4};
#pragma unroll
        for (int q = 0; q < 5; ++q) {
            float v = vals[q];
            for (int off = 32; off > 0; off >>= 1) v += __shfl_xor(v, off);
            if ((tid & 63) == 0) sbuf[(tid >> 6) * 8 + q] = v;
        }
        __syncthreads();
        if (tid < 5) {
            float s = 0.f;
            for (int w = 0; w < 8; ++w) s += sbuf[w * 8 + tid];
            atomicAdd(&ws[ACC_OFF + tid], s);
        }
    }
}

// mask sums (tiny): acc[5] = sum(pmask), acc[6] = sum(zmask)
__global__ void masksum_kernel(const float* __restrict__ pmask,
                               const float* __restrict__ zmask,
                               float* __restrict__ ws) {
    int tid = threadIdx.x;   // 256 threads, 1 block
    float a5 = 0.f, a6 = 0.f;
    for (int v = tid; v < B_ * TP_; v += 256) a5 += pmask[v];
    for (int v = tid; v < B_ * TQ_; v += 256) a6 += zmask[v];
    __shared__ float s5[4], s6[4];
    for (int off = 32; off > 0; off >>= 1) { a5 += __shfl_xor(a5, off); a6 += __shfl_xor(a6, off); }
    if ((tid & 63) == 0) { s5[tid >> 6] = a5; s6[tid >> 6] = a6; }
    __syncthreads();
    if (tid == 0) {
        ws[5] = s5[0] + s5[1] + s5[2] + s5[3];
        ws[6] = s6[0] + s6[1] + s6[2] + s6[3];
    }
}

__global__ void final_kernel(const float* __restrict__ ws,
                             const float* __restrict__ ldl,
                             float* __restrict__ out) {
    if (threadIdx.x == 0 && blockIdx.x == 0) {
        float gen  = ws[0] * (1.f / 32768.f);
        float e2e  = ws[1] * (1.f / 32768.f);
        float fm   = ws[2] * (2.f / 2097152.f);
        float melv = ws[3] * (45.f / 40960.f);
        float durv = ws[4];
        float dlen = logf(ldl[0] + 1e-6f);
        float kl  = (ws[DTW_OFF + 0] + ws[DTW_OFF + 1] + ws[DTW_OFF + 2] + ws[DTW_OFF + 3]) / ws[5];
        float klf = (ws[DTW_OFF + 4] + ws[DTW_OFF + 5] + ws[DTW_OFF + 6] + ws[DTW_OFF + 7]) / ws[6];
        out[0] = gen + e2e + fm + melv + durv + dlen + kl + klf;
    }
}

extern "C" void kernel_launch(void* const* d_in, const int* in_sizes, int n_in,
                              void* d_out, int out_size, void* d_ws, size_t ws_size,
                              hipStream_t stream) {
    const float* mel    = (const float*)d_in[0];
    const float* melh   = (const float*)d_in[1];
    const float* sg     = (const float*)d_in[2];
    const float* se     = (const float*)d_in[3];
    const float* fr     = (const float*)d_in[4];
    const float* ff     = (const float*)d_in[5];
    const float* dur    = (const float*)d_in[6];
    const float* ldl    = (const float*)d_in[7];
    // d_in[8] = loss_pitch (unused by reference)
    const float* z_p    = (const float*)d_in[9];
    const float* m_p    = (const float*)d_in[10];
    const float* logs_p = (const float*)d_in[11];
    const float* z_q    = (const float*)d_in[12];
    const float* m_q    = (const float*)d_in[13];
    const float* logs_q = (const float*)d_in[14];
    const float* pmask  = (const float*)d_in[15];
    const float* zmask  = (const float*)d_in[16];  // (B,1,TQ) == flat (B,TQ)
    float* ws  = (float*)d_ws;
    float* out = (float*)d_out;

    sl_kernel<<<12, 256, 0, stream>>>(logs_p, logs_q, ws);
    masksum_kernel<<<1, 256, 0, stream>>>(pmask, zmask, ws);
    kl_kernel<<<dim3(13, 13, 8), dim3(16, 16), 0, stream>>>(
        m_p, logs_p, z_p, m_q, logs_q, z_q, pmask, zmask, ws);
    main_kernel<<<8 + 1016, 512, 0, stream>>>(mel, melh, sg, se, fr, ff, dur, ws);
    final_kernel<<<1, 64, 0, stream>>>(ws, ldl, out);
}